// Round 10
// baseline (2921.876 us; speedup 1.0000x reference)
//
#include <hip/hip_runtime.h>
#include <hip/hip_bf16.h>
#include <math.h>

// Problem constants
#define BB 16
#define SS 256
#define DD 1024
#define HH 16
#define HDD 64
#define FF 4096
#define LL 6
#define VV 32
#define MM (BB*SS)   // 4096 tokens

using bf16 = __hip_bfloat16;
using short4v = __attribute__((ext_vector_type(4))) short;
using short8 = __attribute__((ext_vector_type(8))) short;
using f32x4  = __attribute__((ext_vector_type(4))) float;

__device__ __forceinline__ float bf2f(short u){
  unsigned int x = ((unsigned int)(unsigned short)u) << 16;
  return __builtin_bit_cast(float, x);
}
__device__ __forceinline__ short f2bf(float f){
  return __builtin_bit_cast(short, __float2bfloat16(f));
}

__device__ __forceinline__ void gll16(const void* g, void* l) {
  __builtin_amdgcn_global_load_lds(
      (const __attribute__((address_space(1))) void*)g,
      (__attribute__((address_space(3))) void*)l,
      16, 0, 0);
}

__device__ __forceinline__ f32x4 mfma16(short8 a, short8 b, f32x4 c){
  return __builtin_amdgcn_mfma_f32_16x16x32_bf16(a, b, c, 0, 0, 0);
}

__device__ __forceinline__ void st_out(float* p, float v){ *p = v; }
__device__ __forceinline__ void st_out(bf16* p, float v){ *p = __float2bfloat16(v); }

// ---------------------------------------------------------------------------
// Tiled transpose + fp32->bf16 convert: in [R][C] fp32 -> out [C][R] bf16.
// ---------------------------------------------------------------------------
__global__ __launch_bounds__(256)
void tcvt64(const float* __restrict__ in, bf16* __restrict__ out,
            int R, int C, long izs, long ozs)
{
  in  += (long)blockIdx.z * izs;
  out += (long)blockIdx.z * ozs;
  __shared__ float tl[64][65];
  int c0 = blockIdx.x * 64, r0 = blockIdx.y * 64;
  int t = threadIdx.x;
  int tr = t >> 4, tc = (t & 15) * 4;
  #pragma unroll
  for (int i = 0; i < 4; ++i) {
    f32x4 v = *(const f32x4*)(in + (long)(r0 + tr + i*16) * C + c0 + tc);
    tl[tr + i*16][tc+0] = v[0];
    tl[tr + i*16][tc+1] = v[1];
    tl[tr + i*16][tc+2] = v[2];
    tl[tr + i*16][tc+3] = v[3];
  }
  __syncthreads();
  int oc = t >> 2, rch = (t & 3) * 16;
  short8 o0, o1;
  #pragma unroll
  for (int j = 0; j < 8; ++j) o0[j] = f2bf(tl[rch + j][oc]);
  #pragma unroll
  for (int j = 0; j < 8; ++j) o1[j] = f2bf(tl[rch + 8 + j][oc]);
  *(short8*)(out + (long)(c0 + oc) * R + r0 + rch)     = o0;
  *(short8*)(out + (long)(c0 + oc) * R + r0 + rch + 8) = o1;
}

// W1/W3 transpose+convert, interleaved row remap for fused SwiGLU.
// grid: (64, 16, 12): z = l*2 + (0:W1, 1:W3)
__global__ __launch_bounds__(256)
void tcvt64_w13(const float* __restrict__ W1, const float* __restrict__ W3,
                bf16* __restrict__ out)
{
  int l = blockIdx.z >> 1;
  const float* in = ((blockIdx.z & 1) ? W3 : W1) + (long)l * 1024 * 4096;
  const int zoff = (blockIdx.z & 1) ? 16 : 0;
  bf16* o = out + (long)l * 8192 * 1024;
  __shared__ float tl[64][65];
  int c0 = blockIdx.x * 64, r0 = blockIdx.y * 64;
  int t = threadIdx.x;
  int tr = t >> 4, tc = (t & 15) * 4;
  #pragma unroll
  for (int i = 0; i < 4; ++i) {
    f32x4 v = *(const f32x4*)(in + (long)(r0 + tr + i*16) * 4096 + c0 + tc);
    tl[tr + i*16][tc+0] = v[0];
    tl[tr + i*16][tc+1] = v[1];
    tl[tr + i*16][tc+2] = v[2];
    tl[tr + i*16][tc+3] = v[3];
  }
  __syncthreads();
  int oc = t >> 2, rch = (t & 3) * 16;
  short8 o0, o1;
  #pragma unroll
  for (int j = 0; j < 8; ++j) o0[j] = f2bf(tl[rch + j][oc]);
  #pragma unroll
  for (int j = 0; j < 8; ++j) o1[j] = f2bf(tl[rch + 8 + j][oc]);
  int n = c0 + oc;
  int orow = ((n >> 4) << 5) + zoff + (n & 15);
  *(short8*)(o + (long)orow * 1024 + r0 + rch)     = o0;
  *(short8*)(o + (long)orow * 1024 + r0 + rch + 8) = o1;
}

// plain fp32 -> bf16 convert; 8 elems/thread
__global__ __launch_bounds__(256)
void cvt(const float* __restrict__ in, bf16* __restrict__ out)
{
  long base = ((long)blockIdx.x * 256 + threadIdx.x) * 8;
  f32x4 a = *(const f32x4*)(in + base);
  f32x4 b = *(const f32x4*)(in + base + 4);
  short8 o;
  #pragma unroll
  for (int j = 0; j < 4; ++j) { o[j] = f2bf(a[j]); o[4+j] = f2bf(b[j]); }
  *(short8*)(out + base) = o;
}

// ---------------------------------------------------------------------------
// 256x256-tile 8-phase bf16 GEMM.
// MODE 0: plain store. MODE 1: fused SwiGLU. MODE 2: QKV with fused
//   V-transpose for branches 0/3 (V-tiles write ONLY vt, skip C).
// ---------------------------------------------------------------------------
template<typename OUT, int MODE>
__global__ __launch_bounds__(512, 2)
void gemm256(const bf16* __restrict__ A, const bf16* __restrict__ Bt,
             OUT* __restrict__ C, int K,
             int lda, int ldb, int ldc, long kzs, long czs, int swz,
             bf16* __restrict__ vtp)
{
  __shared__ short lds[65536];   // 128 KiB
  char* L = (char*)lds;
  A  += (long)blockIdx.z * kzs;
  Bt += (long)blockIdx.z * kzs;
  C  += (long)blockIdx.z * czs;
  int lin = blockIdx.x + gridDim.x * blockIdx.y;
  if (swz) {
    int nwg = gridDim.x * gridDim.y;
    int q = nwg >> 3, r = nwg & 7;
    int xcd = lin & 7, o = lin >> 3;
    lin = (xcd < r ? xcd*(q+1) : r*(q+1) + (xcd-r)*q) + o;
  }
  const int n0 = (lin % gridDim.x) * 256;
  const int m0 = (lin / gridDim.x) * 256;
  const int t = threadIdx.x;
  const int wid = t >> 6, lane = t & 63, lo = lane & 15, hi = lane >> 4;
  const int wr = wid >> 2, wc = wid & 3;
  const int rst = t >> 3;
  const int glog = (t & 7) ^ (rst & 7);
  const int wub = wid * 1024;
  const bf16* Ap = A + (long)m0 * lda + glog * 8;
  const bf16* Bp = Bt + (long)n0 * ldb + glog * 8;
  f32x4 acc[8][4] = {};
  const int nkt = K >> 6;

  auto STAGE = [&](int kt, int p, int d) {
    const long ko = (long)kt * 64;
    char* base = L + d*65536;
    if (p < 2) {
      gll16(Ap + (long)((p*2  )*64 + rst)*lda + ko, base + (p*2  )*8192 + wub);
      gll16(Ap + (long)((p*2+1)*64 + rst)*lda + ko, base + (p*2+1)*8192 + wub);
    } else {
      int pp = p - 2;
      gll16(Bp + (long)((pp*2  )*64 + rst)*ldb + ko, base + 32768 + (pp*2  )*8192 + wub);
      gll16(Bp + (long)((pp*2+1)*64 + rst)*ldb + ko, base + 32768 + (pp*2+1)*8192 + wub);
    }
  };

  #pragma unroll
  for (int p = 0; p < 4; ++p) STAGE(0, p, 0);

  short8 af[4][2], b0[2][2], b1[2][2];
  const int gk0 = ((0*4 + hi) ^ (lo & 7)) << 4;
  const int gk1 = ((1*4 + hi) ^ (lo & 7)) << 4;

  for (int kt = 0; kt < nkt; ++kt) {
    const int d = kt & 1;
    const int ktn = (kt+1 < nkt) ? kt+1 : kt;
    char* Ab = L + d*65536;
    char* Bb = Ab + 32768;
    // ---- phase 0
    STAGE(ktn, 0, d^1);
    __builtin_amdgcn_sched_barrier(0);
    asm volatile("s_waitcnt vmcnt(2)" ::: "memory");
    __builtin_amdgcn_sched_barrier(0);
    __builtin_amdgcn_s_barrier();
    __builtin_amdgcn_sched_barrier(0);
    #pragma unroll
    for (int mi = 0; mi < 4; ++mi) {
      int r = wr*128 + mi*16 + lo;
      af[mi][0] = *(const short8*)(Ab + r*128 + gk0);
      af[mi][1] = *(const short8*)(Ab + r*128 + gk1);
    }
    #pragma unroll
    for (int ni = 0; ni < 2; ++ni) {
      int r = wc*64 + ni*16 + lo;
      b0[ni][0] = *(const short8*)(Bb + r*128 + gk0);
      b0[ni][1] = *(const short8*)(Bb + r*128 + gk1);
    }
    __builtin_amdgcn_s_barrier();
    __builtin_amdgcn_s_setprio(1);
    #pragma unroll
    for (int mi = 0; mi < 4; ++mi)
      #pragma unroll
      for (int ni = 0; ni < 2; ++ni) {
        acc[mi][ni] = mfma16(af[mi][0], b0[ni][0], acc[mi][ni]);
        acc[mi][ni] = mfma16(af[mi][1], b0[ni][1], acc[mi][ni]);
      }
    __builtin_amdgcn_s_setprio(0);
    __builtin_amdgcn_sched_barrier(0);
    __builtin_amdgcn_s_barrier();
    // ---- phase 1
    STAGE(ktn, 1, d^1);
    #pragma unroll
    for (int ni = 0; ni < 2; ++ni) {
      int r = wc*64 + (2+ni)*16 + lo;
      b1[ni][0] = *(const short8*)(Bb + r*128 + gk0);
      b1[ni][1] = *(const short8*)(Bb + r*128 + gk1);
    }
    __builtin_amdgcn_s_barrier();
    __builtin_amdgcn_s_setprio(1);
    #pragma unroll
    for (int mi = 0; mi < 4; ++mi)
      #pragma unroll
      for (int ni = 0; ni < 2; ++ni) {
        acc[mi][2+ni] = mfma16(af[mi][0], b1[ni][0], acc[mi][2+ni]);
        acc[mi][2+ni] = mfma16(af[mi][1], b1[ni][1], acc[mi][2+ni]);
      }
    __builtin_amdgcn_s_setprio(0);
    __builtin_amdgcn_sched_barrier(0);
    __builtin_amdgcn_s_barrier();
    // ---- phase 2
    STAGE(ktn, 2, d^1);
    #pragma unroll
    for (int mi = 0; mi < 4; ++mi) {
      int r = wr*128 + (4+mi)*16 + lo;
      af[mi][0] = *(const short8*)(Ab + r*128 + gk0);
      af[mi][1] = *(const short8*)(Ab + r*128 + gk1);
    }
    __builtin_amdgcn_s_barrier();
    __builtin_amdgcn_s_setprio(1);
    #pragma unroll
    for (int mi = 0; mi < 4; ++mi)
      #pragma unroll
      for (int ni = 0; ni < 2; ++ni) {
        acc[4+mi][2+ni] = mfma16(af[mi][0], b1[ni][0], acc[4+mi][2+ni]);
        acc[4+mi][2+ni] = mfma16(af[mi][1], b1[ni][1], acc[4+mi][2+ni]);
      }
    __builtin_amdgcn_s_setprio(0);
    __builtin_amdgcn_sched_barrier(0);
    __builtin_amdgcn_s_barrier();
    // ---- phase 3
    STAGE(ktn, 3, d^1);
    __builtin_amdgcn_s_barrier();
    __builtin_amdgcn_s_setprio(1);
    #pragma unroll
    for (int mi = 0; mi < 4; ++mi)
      #pragma unroll
      for (int ni = 0; ni < 2; ++ni) {
        acc[4+mi][ni] = mfma16(af[mi][0], b0[ni][0], acc[4+mi][ni]);
        acc[4+mi][ni] = mfma16(af[mi][1], b0[ni][1], acc[4+mi][ni]);
      }
    __builtin_amdgcn_s_setprio(0);
    __builtin_amdgcn_sched_barrier(0);
    __builtin_amdgcn_s_barrier();
  }
  if (MODE == 1) {
    #pragma unroll
    for (int mi = 0; mi < 8; ++mi)
      #pragma unroll
      for (int k = 0; k < 2; ++k)
        #pragma unroll
        for (int r = 0; r < 4; ++r) {
          float h1 = acc[mi][2*k][r], h3 = acc[mi][2*k+1][r];
          float sv = h1 / (1.f + __expf(-h1)) * h3;
          int row = m0 + wr*128 + mi*16 + hi*4 + r;
          int col = (n0 >> 1) + wc*32 + k*16 + lo;
          st_out(C + (long)row * ldc + col, sv);
        }
    return;
  }
  if (MODE == 2) {
    int xt = n0 / 3072, rem = n0 - xt*3072;
    if (rem >= 2048 && (xt == 0 || xt == 3)) {
      const int xc = xt ? 1 : 0;
      const int b = m0 >> 8;
      #pragma unroll
      for (int mi = 0; mi < 8; ++mi)
        #pragma unroll
        for (int ni = 0; ni < 4; ++ni) {
          int col = n0 + wc*64 + ni*16 + lo;
          int hd = col - xt*3072 - 2048;
          int h = hd >> 6, dd = hd & 63;
          int trow = wr*128 + mi*16 + hi*4;
          short4v pk;
          #pragma unroll
          for (int r = 0; r < 4; ++r) pk[r] = f2bf(acc[mi][ni][r]);
          *(short4v*)(vtp + ((long)((xc<<8)+(b<<4)+h)*64 + dd)*256 + trow) = pk;
        }
      return;
    }
  }
  #pragma unroll
  for (int mi = 0; mi < 8; ++mi)
    #pragma unroll
    for (int ni = 0; ni < 4; ++ni)
      #pragma unroll
      for (int r = 0; r < 4; ++r) {
        int row = m0 + wr*128 + mi*16 + hi*4 + r;
        int col = n0 + wc*64 + ni*16 + lo;
        st_out(C + (long)row * ldc + col, acc[mi][ni][r]);
      }
}

// ---------------------------------------------------------------------------
// bf16 GEMM 128x128 (used for the small batched Wof precompute).
// ---------------------------------------------------------------------------
template<typename OUT>
__global__ __launch_bounds__(256)
void gemm_bt(const bf16* __restrict__ A, const bf16* __restrict__ Bt,
             OUT* __restrict__ C, int M, int N, int K,
             int lda, int ldb, int ldc,
             long azs, long bzs, long czs, int zdiv,
             long azs2, long bzs2, long czs2)
{
  const int z1 = blockIdx.z % zdiv, z2 = blockIdx.z / zdiv;
  A  += (long)z1 * azs + (long)z2 * azs2;
  Bt += (long)z1 * bzs + (long)z2 * bzs2;
  C  += (long)z1 * czs + (long)z2 * czs2;
  const int n0 = blockIdx.x * 128;
  const int m0 = blockIdx.y * 128;
  __shared__ short As[128*64];
  __shared__ short Bs[128*64];
  char* AsB = (char*)As;
  char* BsB = (char*)Bs;
  const int t = threadIdx.x;
  const int wid = t >> 6, lane = t & 63, lo = lane & 15, hi = lane >> 4;
  const int wr = wid >> 1, wc = wid & 1;
  const int rst  = t >> 3;
  const int glog = (t & 7) ^ (rst & 7);
  const int ldsbase = wid * 1024;
  f32x4 acc[4][4] = {};
  const bf16* Ap = A + (long)m0 * lda + glog * 8;
  const bf16* Bp = Bt + (long)n0 * ldb + glog * 8;
  const int nkt = K >> 6;
  for (int kt = 0; kt < nkt; ++kt) {
    const long ko = (long)kt * 64;
    #pragma unroll
    for (int i = 0; i < 4; ++i)
      gll16(Ap + (long)(i*32 + rst) * lda + ko, AsB + i*4096 + ldsbase);
    #pragma unroll
    for (int i = 0; i < 4; ++i)
      gll16(Bp + (long)(i*32 + rst) * ldb + ko, BsB + i*4096 + ldsbase);
    __syncthreads();
    #pragma unroll
    for (int kk = 0; kk < 2; ++kk) {
      const int g = ((kk*4 + hi) ^ (lo & 7)) << 4;
      short8 af[4], bfv[4];
      #pragma unroll
      for (int mi = 0; mi < 4; ++mi) {
        int r = wr*64 + mi*16 + lo;
        af[mi] = *(const short8*)(AsB + r*128 + g);
      }
      #pragma unroll
      for (int ni = 0; ni < 4; ++ni) {
        int r = wc*64 + ni*16 + lo;
        bfv[ni] = *(const short8*)(BsB + r*128 + g);
      }
      #pragma unroll
      for (int mi = 0; mi < 4; ++mi)
        #pragma unroll
        for (int ni = 0; ni < 4; ++ni)
          acc[mi][ni] = mfma16(af[mi], bfv[ni], acc[mi][ni]);
    }
    __syncthreads();
  }
  #pragma unroll
  for (int mi = 0; mi < 4; ++mi)
    #pragma unroll
    for (int ni = 0; ni < 4; ++ni)
      #pragma unroll
      for (int r = 0; r < 4; ++r) {
        int row = m0 + wr*64 + mi*16 + hi*4 + r;
        int col = n0 + wc*64 + ni*16 + lo;
        st_out(C + (long)row * ldc + col, acc[mi][ni][r]);
      }
}

// ---------------------------------------------------------------------------
// Fused attention kernel. grid (256, 3):
//  y in {0,1}: flash attention (flat softmax) for branch x = y*3 (0 or 3).
//  y == 2:    analytic branches 1 (chain) and 2 (pair); each wave handles
//             4 tokens x 16 heads.
// ---------------------------------------------------------------------------
__global__ __launch_bounds__(256)
void attn_k(const bf16* __restrict__ qkv, const bf16* __restrict__ vt,
            bf16* __restrict__ ctx)
{
  __shared__ short Pl[4][64*64];
  const int bh = blockIdx.x;
  const int t = threadIdx.x, wid = t >> 6, lane = t & 63;

  if (blockIdx.y == 2) {
    // ---- branches 1 & 2, analytic ----
    const unsigned short* Q = (const unsigned short*)qkv;
    const int base_tok = bh * 16 + wid * 4;
    for (int ti = 0; ti < 4; ++ti) {
      const int gtok = base_tok + ti;
      const int b = gtok >> 8, i = gtok & 255;
      const long rowQ = (long)gtok * 12288;
      const long rb = (long)(b*SS) * 12288;
      const int jm = i > 0 ? i-1 : 0;
      const int jp = i < SS-1 ? i+1 : SS-1;
      const int j0 = i & ~1, j1 = j0 | 1;
      unsigned short* outp = (unsigned short*)ctx + (long)gtok * 4096;
      #pragma unroll 2
      for (int h = 0; h < HH; ++h) {
        const int off1 = 3072 + h*64 + lane;
        const int off2 = 6144 + h*64 + lane;
        float q1d = bf2f(Q[rowQ + off1]);
        float q2d = bf2f(Q[rowQ + off2]);
        float km = bf2f(Q[rb + (long)jm*12288 + off1 + 1024]);
        float k0 = bf2f(Q[rb + (long)i *12288 + off1 + 1024]);
        float kp = bf2f(Q[rb + (long)jp*12288 + off1 + 1024]);
        float ka = bf2f(Q[rb + (long)j0*12288 + off2 + 1024]);
        float kb_ = bf2f(Q[rb + (long)j1*12288 + off2 + 1024]);
        float s0 = q1d*km, s1 = q1d*k0, s2 = q1d*kp, s3 = q2d*ka, s4 = q2d*kb_;
        #pragma unroll
        for (int st = 1; st < 64; st <<= 1) {
          s0 += __shfl_xor(s0, st); s1 += __shfl_xor(s1, st); s2 += __shfl_xor(s2, st);
          s3 += __shfl_xor(s3, st); s4 += __shfl_xor(s4, st);
        }
        float lm = s0*0.125f + (i > 0      ? 0.f : -1e30f);
        float l0 = s1*0.125f;
        float lp = s2*0.125f + (i < SS-1   ? 0.f : -1e30f);
        float pm = __expf(lm), p0 = __expf(l0), pp = __expf(lp);
        float vm = bf2f(Q[rb + (long)jm*12288 + off1 + 2048]);
        float v0 = bf2f(Q[rb + (long)i *12288 + off1 + 2048]);
        float vp = bf2f(Q[rb + (long)jp*12288 + off1 + 2048]);
        float o1 = (pm*vm + p0*v0 + pp*vp) / (pm+p0+pp);
        float la = s3*0.125f, lb = s4*0.125f;
        float pa = __expf(la), pb = __expf(lb);
        float va = bf2f(Q[rb + (long)j0*12288 + off2 + 2048]);
        float vb2= bf2f(Q[rb + (long)j1*12288 + off2 + 2048]);
        float o2 = (pa*va + pb*vb2) / (pa+pb);
        outp[1024 + h*64 + lane] = (unsigned short)f2bf(o1);
        outp[2048 + h*64 + lane] = (unsigned short)f2bf(o2);
      }
    }
    return;
  }

  // ---- flash attention, branches 0 / 3 (flat softmax) ----
  const int xc = blockIdx.y;
  const int x = xc * 3;
  const int b = bh >> 4, h = bh & 15;
  const int lo = lane & 15, hi = lane >> 4;
  const int q0 = wid * 64;
  const float bsc = (xc == 0) ? -0.05f : 0.0f;
  char* P = (char*)Pl[wid];
  const bf16* qb = qkv + (long)(b*SS) * 12288 + x*3072 + h*64;
  const bf16* kb = qb + 1024;
  const bf16* vb = vt + (long)(xc*256 + b*16 + h) * 64 * 256;

  short8 qf[4][2];
  #pragma unroll
  for (int mi = 0; mi < 4; ++mi)
    #pragma unroll
    for (int kk = 0; kk < 2; ++kk)
      qf[mi][kk] = *(const short8*)(qb + (long)(q0 + mi*16 + lo) * 12288 + kk*32 + hi*8);

  float sr[4][4];
  f32x4 aco[4][4] = {};
  #pragma unroll
  for (int i = 0; i < 4; ++i)
    #pragma unroll
    for (int r = 0; r < 4; ++r) sr[i][r] = 0.f;

  for (int c = 0; c < 4; ++c) {
    f32x4 acc[4][4] = {};
    #pragma unroll
    for (int kk = 0; kk < 2; ++kk) {
      short8 bfv[4];
      #pragma unroll
      for (int ni = 0; ni < 4; ++ni)
        bfv[ni] = *(const short8*)(kb + (long)(c*64 + ni*16 + lo) * 12288 + kk*32 + hi*8);
      #pragma unroll
      for (int mi = 0; mi < 4; ++mi)
        #pragma unroll
        for (int ni = 0; ni < 4; ++ni)
          acc[mi][ni] = mfma16(qf[mi][kk], bfv[ni], acc[mi][ni]);
    }
    // flat softmax numerator: P = exp(s/8 + bias), accumulate row sums
    #pragma unroll
    for (int mi = 0; mi < 4; ++mi)
      #pragma unroll
      for (int ni = 0; ni < 4; ++ni)
        #pragma unroll
        for (int r = 0; r < 4; ++r) {
          int lqq = mi*16 + hi*4 + r;          // local q row in wave tile
          int qq = q0 + lqq;                   // global q row
          int ttl = ni*16 + lo;                // LOCAL col within chunk
          int tt = c*64 + ttl;                 // global col (bias only)
          float s = fmaf(fabsf((float)(qq - tt)), bsc, acc[mi][ni][r] * 0.125f);
          float pv = __expf(s);
          sr[mi][r] += pv;
          int gph = ((ttl >> 3) ^ (lqq & 7)) << 4;
          *(bf16*)(P + lqq*128 + gph + (ttl & 7)*2) = __float2bfloat16(pv);
        }
    // PV
    #pragma unroll
    for (int kk = 0; kk < 2; ++kk) {
      short8 pf[4], vf[4];
      #pragma unroll
      for (int mi = 0; mi < 4; ++mi) {
        int qq = mi*16 + lo;
        int gph = ((kk*4 + hi) ^ (qq & 7)) << 4;
        pf[mi] = *(const short8*)(P + qq*128 + gph);
      }
      #pragma unroll
      for (int di = 0; di < 4; ++di)
        vf[di] = *(const short8*)(vb + (long)(di*16 + lo) * 256 + c*64 + kk*32 + hi*8);
      #pragma unroll
      for (int mi = 0; mi < 4; ++mi)
        #pragma unroll
        for (int di = 0; di < 4; ++di)
          aco[mi][di] = mfma16(pf[mi], vf[di], aco[mi][di]);
    }
  }
  // final row-sum reduce and write ctx (K-concat layout, ld=4096)
  #pragma unroll
  for (int mi = 0; mi < 4; ++mi)
    #pragma unroll
    for (int r = 0; r < 4; ++r) {
      float s = sr[mi][r];
      #pragma unroll
      for (int d = 1; d < 16; d <<= 1) s += __shfl_xor(s, d);
      sr[mi][r] = s;
    }
  bf16* cb = ctx + (long)(b*SS) * 4096 + x*1024 + h*64;
  #pragma unroll
  for (int mi = 0; mi < 4; ++mi)
    #pragma unroll
    for (int di = 0; di < 4; ++di)
      #pragma unroll
      for (int r = 0; r < 4; ++r) {
        int row = q0 + mi*16 + hi*4 + r;
        int col = di*16 + lo;
        cb[(long)row * 4096 + col] = __float2bfloat16(aco[mi][di][r] / sr[mi][r]);
      }
}

// ---------------------------------------------------------------------------
// Fused residual + LayerNorm + adaLN modulation.
//   v = xin + gate*(sum_{j<ycnt} y_j + ybias)   (y: bf16 partials; null => v=xin)
// ---------------------------------------------------------------------------
__global__ __launch_bounds__(256)
void ln_fused(const float* __restrict__ xin, const bf16* __restrict__ y,
              int ycnt, long ystride,
              const float* __restrict__ ybias, const float* __restrict__ gate,
              const float* __restrict__ lnw, const float* __restrict__ lnb,
              const float* __restrict__ sc, const float* __restrict__ sh,
              float* __restrict__ xout, bf16* __restrict__ xnbf,
              float* __restrict__ xnf)
{
  int row = blockIdx.x;
  int b = row >> 8;
  int t = threadIdx.x;
  int d0 = t * 4;
  const float* xr = xin + (long)row * DD;
  f32x4 xi = *(const f32x4*)(xr + d0);
  float v[4];
  if (y) {
    f32x4 ys = {};
    for (int jp = 0; jp < ycnt; ++jp) {
      short4v yv = *(const short4v*)(y + jp*ystride + (long)row * DD + d0);
      #pragma unroll
      for (int j = 0; j < 4; ++j) ys[j] += bf2f(yv[j]);
    }
    #pragma unroll
    for (int j = 0; j < 4; ++j) {
      float yy = ys[j] + (ybias ? ybias[d0+j] : 0.f);
      v[j] = xi[j] + gate[b*6144 + d0 + j] * yy;
    }
  } else {
    #pragma unroll
    for (int j = 0; j < 4; ++j) v[j] = xi[j];
  }
  if (xout) {
    f32x4 o; o[0]=v[0]; o[1]=v[1]; o[2]=v[2]; o[3]=v[3];
    *(f32x4*)(xout + (long)row * DD + d0) = o;
  }
  float s = v[0]+v[1]+v[2]+v[3];
  float s2 = v[0]*v[0]+v[1]*v[1]+v[2]*v[2]+v[3]*v[3];
  #pragma unroll
  for (int d = 1; d < 64; d <<= 1) { s += __shfl_xor(s, d); s2 += __shfl_xor(s2, d); }
  __shared__ float rs[4][2];
  int wid = t >> 6, lane = t & 63;
  if (lane == 0) { rs[wid][0] = s; rs[wid][1] = s2; }
  __syncthreads();
  s  = rs[0][0]+rs[1][0]+rs[2][0]+rs[3][0];
  s2 = rs[0][1]+rs[1][1]+rs[2][1]+rs[3][1];
  float mean = s * (1.f/1024.f);
  float var  = s2 * (1.f/1024.f) - mean*mean;
  float rstd = rsqrtf(var + 1e-6f);
  #pragma unroll
  for (int j = 0; j < 4; ++j) {
    int d = d0 + j;
    float xn = (v[j] - mean) * rstd * lnw[d] + lnb[d];
    if (sc) {
      float val = xn * (1.f + sc[b*6144 + d]) + sh[b*6144 + d];
      xnbf[(long)row * DD + d] = __float2bfloat16(val);
    } else if (xnbf) {
      xnbf[(long)row * DD + d] = __float2bfloat16(xn);
    } else {
      xnf[(long)row * DD + d] = xn;
    }
  }
}

// ---------------------------------------------------------------------------
// adaLN: fused silu(t_emb) + split-K partial GEMM, then reduce.
// a_gemm grid: (6 nblk, 8 kc, 6 l)
// ---------------------------------------------------------------------------
__global__ __launch_bounds__(256)
void a_gemm(const float* __restrict__ Wa, const float* __restrict__ te,
            float* __restrict__ partial)
{
  int l = blockIdx.z, kc = blockIdx.y;
  int n0 = (blockIdx.x * 256 + threadIdx.x) * 4;
  __shared__ float sl[16*128];
  for (int i = threadIdx.x; i < 16*128; i += 256) {
    int m = i >> 7, k = i & 127;
    float v = te[m*1024 + kc*128 + k];
    sl[i] = v / (1.f + __expf(-v));        // fused SiLU
  }
  __syncthreads();
  f32x4 acc[16] = {};
  const float* wp = Wa + (long)l * DD * 6144 + (long)(kc*128) * 6144 + n0;
  #pragma unroll 4
  for (int k = 0; k < 128; ++k) {
    f32x4 w = *(const f32x4*)(wp + (long)k * 6144);
    #pragma unroll
    for (int m = 0; m < 16; ++m) {
      float sv = sl[m*128 + k];
      #pragma unroll
      for (int j = 0; j < 4; ++j) acc[m][j] += sv * w[j];
    }
  }
  #pragma unroll
  for (int m = 0; m < 16; ++m)
    *(f32x4*)(partial + ((long)(l*8 + kc)*16 + m) * 6144 + n0) = acc[m];
}

__global__ __launch_bounds__(256)
void a_red(const float* __restrict__ partial, const float* __restrict__ ba,
           float* __restrict__ a_all)
{
  int idx = blockIdx.x * 256 + threadIdx.x;
  int n = idx % 6144;
  int lm = idx / 6144;
  int l = lm >> 4, m = lm & 15;
  float s = 0.f;
  #pragma unroll
  for (int kc = 0; kc < 8; ++kc)
    s += partial[((long)(l*8 + kc)*16 + m) * 6144 + n];
  a_all[(long)(l*16 + m) * 6144 + n] = s + ba[(long)l * 6144 + n];
}

// ---------------------------------------------------------------------------
// Final projection
// ---------------------------------------------------------------------------
__global__ __launch_bounds__(256)
void proj_k(const float* __restrict__ xnf, const float* __restrict__ Wp,
            const float* __restrict__ bp, float* __restrict__ out)
{
  int v = threadIdx.x & 31, tg = threadIdx.x >> 5;
  int s = blockIdx.x * 8 + tg;
  const float* xr = xnf + (long)s * DD;
  float acc = bp[v];
  #pragma unroll 8
  for (int k = 0; k < DD; ++k) acc += xr[k] * Wp[(long)k * VV + v];
  out[(long)s * VV + v] = acc;
}

// ---------------------------------------------------------------------------
extern "C" void kernel_launch(void* const* d_in, const int* in_sizes, int n_in,
                              void* d_out, int out_size, void* d_ws, size_t ws_size,
                              hipStream_t stream)
{
  (void)in_sizes; (void)n_in; (void)out_size; (void)ws_size;
  const float* x_in = (const float*)d_in[0];
  const float* t_emb= (const float*)d_in[1];
  const float* ln1w = (const float*)d_in[2];
  const float* ln1b = (const float*)d_in[3];
  const float* ln2w = (const float*)d_in[4];
  const float* ln2b = (const float*)d_in[5];
  const float* Wqkv = (const float*)d_in[6];
  const float* Wo   = (const float*)d_in[7];
  const float* Wf   = (const float*)d_in[8];
  const float* bfb  = (const float*)d_in[9];
  const float* W1   = (const float*)d_in[10];
  const float* W3   = (const float*)d_in[11];
  const float* W2   = (const float*)d_in[12];
  const float* Wa   = (const float*)d_in[13];
  const float* ba   = (const float*)d_in[14];
  const float* fnw  = (const float*)d_in[15];
  const float* fnb  = (const float*)d_in[16];
  const float* Wp   = (const float*)d_in[17];
  const float* bp   = (const float*)d_in[18];
  float* out = (float*)d_out;

  char* p = (char*)d_ws;
  auto alloc = [&](size_t bytes) { char* r = p; p += (bytes + 255) & ~(size_t)255; return r; };
  bf16* wqkv_t = (bf16*)alloc(6L*4*3072*1024*2);
  bf16* wo_b   = (bf16*)alloc(6L*4*1024*1024*2);
  bf16* wf_t   = (bf16*)alloc(6L*1024*4096*2);
  bf16* wof_t  = (bf16*)alloc(6L*1024*4096*2);
  bf16* w13i_t = (bf16*)alloc(6L*8192*1024*2);
  bf16* w2_t   = (bf16*)alloc(6L*1024*4096*2);
  float* a_all = (float*)alloc(6L*16*6144*4);
  float* a_par = (float*)alloc(6L*8*16*6144*4);
  float* x_buf = (float*)alloc((long)MM*DD*4);
  bf16* xn     = (bf16*)alloc((long)MM*DD*2);
  char* bufA   = alloc((long)MM*12288*2);          // qkv
  bf16* vt     = (bf16*)alloc(2L*16*16*64*256*2);
  bf16* ctx    = (bf16*)alloc((long)MM*4096*2);    // K-concat layout
  char* bufB   = alloc((long)MM*4096*2);           // hg | xnf(fp32)
  bf16* gy     = (bf16*)alloc(4L*MM*DD*2);         // 4 bf16 split-K partials

  bf16* qkvb = (bf16*)bufA;
  bf16* hg   = (bf16*)bufB;
  float* xnf = (float*)bufB;
  const long MMDD = (long)MM*DD;

  // --- upfront: adaLN + ALL weight conversions (batched across layers) ---
  a_gemm<<<dim3(6, 8, 6), 256, 0, stream>>>(Wa, t_emb, a_par);
  a_red<<<dim3(2304), 256, 0, stream>>>(a_par, ba, a_all);
  tcvt64<<<dim3(48,16,24),256,0,stream>>>(Wqkv, wqkv_t, 1024, 3072, 1024L*3072, 3072L*1024);
  cvt<<<dim3(12288),256,0,stream>>>(Wo, wo_b);
  tcvt64<<<dim3(16,64,6),256,0,stream>>>(Wf, wf_t, 4096, 1024, 4096L*1024, 4096L*1024);
  tcvt64_w13<<<dim3(64,16,12),256,0,stream>>>(W1, W3, w13i_t);
  tcvt64<<<dim3(16,64,6),256,0,stream>>>(W2, w2_t, 4096, 1024, 4096L*1024, 4096L*1024);
  // Wof[l][x] = Wo_lx @ Wf_lx-block (stored transposed): z = l*4 + x
  gemm_bt<bf16><<<dim3(8,8,24),256,0,stream>>>(wf_t, wo_b, wof_t,
      1024, 1024, 1024, 4096, 1024, 4096,
      1024L, 1024L*1024, 1024L, 4,
      1024L*4096, 4L*1024*1024, 1024L*4096);

  const long aL = 16L * 6144;
  ln_fused<<<4096,256,0,stream>>>(x_in, nullptr, 0, 0, nullptr, nullptr,
                                  ln1w, ln1b, a_all+1024, a_all+0,
                                  nullptr, xn, nullptr);

  for (int l = 0; l < LL; ++l) {
    const float* a_l = a_all + (long)l * aL;
    // QKV with fused V-transpose for branches 0/3
    gemm256<bf16,2><<<dim3(48,16,1),512,0,stream>>>(xn, wqkv_t + (long)l*4*3072*1024,
        qkvb, 1024, 1024, 1024, 12288, 0, 0, 1, vt);
    // fused: flash attention (y=0,1) + analytic branches 1/2 (y=2)
    attn_k<<<dim3(256,3),256,0,stream>>>(qkvb, vt, ctx);
    // gy[z] = ctx @ Wof (split-K=4, bf16 partials)
    gemm256<bf16,0><<<dim3(4,16,4),512,0,stream>>>(ctx, wof_t + (long)l*1024*4096,
        gy, 1024, 4096, 4096, 1024, 1024L, MMDD, 0, nullptr);
    ln_fused<<<4096,256,0,stream>>>(l ? x_buf : x_in, gy, 4, MMDD,
                                    bfb + (long)l*1024, a_l+2048,
                                    ln2w + (long)l*1024, ln2b + (long)l*1024,
                                    a_l+4096, a_l+3072, x_buf, xn, nullptr);
    // hg = swiglu(xn @ W13) fused
    gemm256<bf16,1><<<dim3(32,16,1),512,0,stream>>>(xn, w13i_t + (long)l*8192*1024,
        hg, 1024, 1024, 1024, 4096, 0, 0, 1, nullptr);
    // gy[z] = hg @ W2 (split-K=4, bf16 partials)
    gemm256<bf16,0><<<dim3(4,16,4),512,0,stream>>>(hg, w2_t + (long)l*1024*4096,
        gy, 1024, 4096, 4096, 1024, 1024L, MMDD, 0, nullptr);
    if (l < LL-1)
      ln_fused<<<4096,256,0,stream>>>(x_buf, gy, 4, MMDD, nullptr, a_l+5120,
                                      ln1w + (long)(l+1)*1024, ln1b + (long)(l+1)*1024,
                                      a_all + (long)(l+1)*aL + 1024, a_all + (long)(l+1)*aL,
                                      x_buf, xn, nullptr);
    else
      ln_fused<<<4096,256,0,stream>>>(x_buf, gy, 4, MMDD, nullptr, a_l+5120,
                                      fnw, fnb, nullptr, nullptr,
                                      x_buf, nullptr, xnf);
  }
  proj_k<<<dim3(512),256,0,stream>>>(xnf, Wp, bp, out);
}

// Round 11
// 2829.753 us; speedup vs baseline: 1.0326x; 1.0326x over previous
//
#include <hip/hip_runtime.h>
#include <hip/hip_bf16.h>
#include <math.h>

// Problem constants
#define BB 16
#define SS 256
#define DD 1024
#define HH 16
#define HDD 64
#define FF 4096
#define LL 6
#define VV 32
#define MM (BB*SS)   // 4096 tokens

using bf16 = __hip_bfloat16;
using short4v = __attribute__((ext_vector_type(4))) short;
using short8 = __attribute__((ext_vector_type(8))) short;
using f32x4  = __attribute__((ext_vector_type(4))) float;

__device__ __forceinline__ float bf2f(short u){
  unsigned int x = ((unsigned int)(unsigned short)u) << 16;
  return __builtin_bit_cast(float, x);
}
__device__ __forceinline__ short f2bf(float f){
  return __builtin_bit_cast(short, __float2bfloat16(f));
}

__device__ __forceinline__ void gll16(const void* g, void* l) {
  __builtin_amdgcn_global_load_lds(
      (const __attribute__((address_space(1))) void*)g,
      (__attribute__((address_space(3))) void*)l,
      16, 0, 0);
}

__device__ __forceinline__ f32x4 mfma16(short8 a, short8 b, f32x4 c){
  return __builtin_amdgcn_mfma_f32_16x16x32_bf16(a, b, c, 0, 0, 0);
}

__device__ __forceinline__ void st_out(float* p, float v){ *p = v; }
__device__ __forceinline__ void st_out(bf16* p, float v){ *p = __float2bfloat16(v); }

// ---------------------------------------------------------------------------
// Tiled transpose + fp32->bf16 convert: in [R][C] fp32 -> out [C][R] bf16.
// ---------------------------------------------------------------------------
__global__ __launch_bounds__(256)
void tcvt64(const float* __restrict__ in, bf16* __restrict__ out,
            int R, int C, long izs, long ozs)
{
  in  += (long)blockIdx.z * izs;
  out += (long)blockIdx.z * ozs;
  __shared__ float tl[64][65];
  int c0 = blockIdx.x * 64, r0 = blockIdx.y * 64;
  int t = threadIdx.x;
  int tr = t >> 4, tc = (t & 15) * 4;
  #pragma unroll
  for (int i = 0; i < 4; ++i) {
    f32x4 v = *(const f32x4*)(in + (long)(r0 + tr + i*16) * C + c0 + tc);
    tl[tr + i*16][tc+0] = v[0];
    tl[tr + i*16][tc+1] = v[1];
    tl[tr + i*16][tc+2] = v[2];
    tl[tr + i*16][tc+3] = v[3];
  }
  __syncthreads();
  int oc = t >> 2, rch = (t & 3) * 16;
  short8 o0, o1;
  #pragma unroll
  for (int j = 0; j < 8; ++j) o0[j] = f2bf(tl[rch + j][oc]);
  #pragma unroll
  for (int j = 0; j < 8; ++j) o1[j] = f2bf(tl[rch + 8 + j][oc]);
  *(short8*)(out + (long)(c0 + oc) * R + r0 + rch)     = o0;
  *(short8*)(out + (long)(c0 + oc) * R + r0 + rch + 8) = o1;
}

// W1/W3 transpose+convert, interleaved row remap for fused SwiGLU.
// grid: (64, 16, 12): z = l*2 + (0:W1, 1:W3)
__global__ __launch_bounds__(256)
void tcvt64_w13(const float* __restrict__ W1, const float* __restrict__ W3,
                bf16* __restrict__ out)
{
  int l = blockIdx.z >> 1;
  const float* in = ((blockIdx.z & 1) ? W3 : W1) + (long)l * 1024 * 4096;
  const int zoff = (blockIdx.z & 1) ? 16 : 0;
  bf16* o = out + (long)l * 8192 * 1024;
  __shared__ float tl[64][65];
  int c0 = blockIdx.x * 64, r0 = blockIdx.y * 64;
  int t = threadIdx.x;
  int tr = t >> 4, tc = (t & 15) * 4;
  #pragma unroll
  for (int i = 0; i < 4; ++i) {
    f32x4 v = *(const f32x4*)(in + (long)(r0 + tr + i*16) * 4096 + c0 + tc);
    tl[tr + i*16][tc+0] = v[0];
    tl[tr + i*16][tc+1] = v[1];
    tl[tr + i*16][tc+2] = v[2];
    tl[tr + i*16][tc+3] = v[3];
  }
  __syncthreads();
  int oc = t >> 2, rch = (t & 3) * 16;
  short8 o0, o1;
  #pragma unroll
  for (int j = 0; j < 8; ++j) o0[j] = f2bf(tl[rch + j][oc]);
  #pragma unroll
  for (int j = 0; j < 8; ++j) o1[j] = f2bf(tl[rch + 8 + j][oc]);
  int n = c0 + oc;
  int orow = ((n >> 4) << 5) + zoff + (n & 15);
  *(short8*)(o + (long)orow * 1024 + r0 + rch)     = o0;
  *(short8*)(o + (long)orow * 1024 + r0 + rch + 8) = o1;
}

// plain fp32 -> bf16 convert; 8 elems/thread
__global__ __launch_bounds__(256)
void cvt(const float* __restrict__ in, bf16* __restrict__ out)
{
  long base = ((long)blockIdx.x * 256 + threadIdx.x) * 8;
  f32x4 a = *(const f32x4*)(in + base);
  f32x4 b = *(const f32x4*)(in + base + 4);
  short8 o;
  #pragma unroll
  for (int j = 0; j < 4; ++j) { o[j] = f2bf(a[j]); o[4+j] = f2bf(b[j]); }
  *(short8*)(out + base) = o;
}

// ---------------------------------------------------------------------------
// 256x256-tile 8-phase bf16 GEMM.
// MODE 0: plain store. MODE 1: fused SwiGLU. MODE 2: QKV with fused
//   V-transpose for branches 0/3 (V-tiles write ONLY vt, skip C).
// ---------------------------------------------------------------------------
template<typename OUT, int MODE>
__global__ __launch_bounds__(512, 2)
void gemm256(const bf16* __restrict__ A, const bf16* __restrict__ Bt,
             OUT* __restrict__ C, int K,
             int lda, int ldb, int ldc, long kzs, long czs, int swz,
             bf16* __restrict__ vtp)
{
  __shared__ short lds[65536];   // 128 KiB
  char* L = (char*)lds;
  A  += (long)blockIdx.z * kzs;
  Bt += (long)blockIdx.z * kzs;
  C  += (long)blockIdx.z * czs;
  int lin = blockIdx.x + gridDim.x * blockIdx.y;
  if (swz) {
    int nwg = gridDim.x * gridDim.y;
    int q = nwg >> 3, r = nwg & 7;
    int xcd = lin & 7, o = lin >> 3;
    lin = (xcd < r ? xcd*(q+1) : r*(q+1) + (xcd-r)*q) + o;
  }
  const int n0 = (lin % gridDim.x) * 256;
  const int m0 = (lin / gridDim.x) * 256;
  const int t = threadIdx.x;
  const int wid = t >> 6, lane = t & 63, lo = lane & 15, hi = lane >> 4;
  const int wr = wid >> 2, wc = wid & 3;
  const int rst = t >> 3;
  const int glog = (t & 7) ^ (rst & 7);
  const int wub = wid * 1024;
  const bf16* Ap = A + (long)m0 * lda + glog * 8;
  const bf16* Bp = Bt + (long)n0 * ldb + glog * 8;
  f32x4 acc[8][4] = {};
  const int nkt = K >> 6;

  auto STAGE = [&](int kt, int p, int d) {
    const long ko = (long)kt * 64;
    char* base = L + d*65536;
    if (p < 2) {
      gll16(Ap + (long)((p*2  )*64 + rst)*lda + ko, base + (p*2  )*8192 + wub);
      gll16(Ap + (long)((p*2+1)*64 + rst)*lda + ko, base + (p*2+1)*8192 + wub);
    } else {
      int pp = p - 2;
      gll16(Bp + (long)((pp*2  )*64 + rst)*ldb + ko, base + 32768 + (pp*2  )*8192 + wub);
      gll16(Bp + (long)((pp*2+1)*64 + rst)*ldb + ko, base + 32768 + (pp*2+1)*8192 + wub);
    }
  };

  #pragma unroll
  for (int p = 0; p < 4; ++p) STAGE(0, p, 0);

  short8 af[4][2], b0[2][2], b1[2][2];
  const int gk0 = ((0*4 + hi) ^ (lo & 7)) << 4;
  const int gk1 = ((1*4 + hi) ^ (lo & 7)) << 4;

  for (int kt = 0; kt < nkt; ++kt) {
    const int d = kt & 1;
    const int ktn = (kt+1 < nkt) ? kt+1 : kt;
    char* Ab = L + d*65536;
    char* Bb = Ab + 32768;
    // ---- phase 0
    STAGE(ktn, 0, d^1);
    __builtin_amdgcn_sched_barrier(0);
    asm volatile("s_waitcnt vmcnt(2)" ::: "memory");
    __builtin_amdgcn_sched_barrier(0);
    __builtin_amdgcn_s_barrier();
    __builtin_amdgcn_sched_barrier(0);
    #pragma unroll
    for (int mi = 0; mi < 4; ++mi) {
      int r = wr*128 + mi*16 + lo;
      af[mi][0] = *(const short8*)(Ab + r*128 + gk0);
      af[mi][1] = *(const short8*)(Ab + r*128 + gk1);
    }
    #pragma unroll
    for (int ni = 0; ni < 2; ++ni) {
      int r = wc*64 + ni*16 + lo;
      b0[ni][0] = *(const short8*)(Bb + r*128 + gk0);
      b0[ni][1] = *(const short8*)(Bb + r*128 + gk1);
    }
    __builtin_amdgcn_s_barrier();
    __builtin_amdgcn_s_setprio(1);
    #pragma unroll
    for (int mi = 0; mi < 4; ++mi)
      #pragma unroll
      for (int ni = 0; ni < 2; ++ni) {
        acc[mi][ni] = mfma16(af[mi][0], b0[ni][0], acc[mi][ni]);
        acc[mi][ni] = mfma16(af[mi][1], b0[ni][1], acc[mi][ni]);
      }
    __builtin_amdgcn_s_setprio(0);
    __builtin_amdgcn_sched_barrier(0);
    __builtin_amdgcn_s_barrier();
    // ---- phase 1
    STAGE(ktn, 1, d^1);
    #pragma unroll
    for (int ni = 0; ni < 2; ++ni) {
      int r = wc*64 + (2+ni)*16 + lo;
      b1[ni][0] = *(const short8*)(Bb + r*128 + gk0);
      b1[ni][1] = *(const short8*)(Bb + r*128 + gk1);
    }
    __builtin_amdgcn_s_barrier();
    __builtin_amdgcn_s_setprio(1);
    #pragma unroll
    for (int mi = 0; mi < 4; ++mi)
      #pragma unroll
      for (int ni = 0; ni < 2; ++ni) {
        acc[mi][2+ni] = mfma16(af[mi][0], b1[ni][0], acc[mi][2+ni]);
        acc[mi][2+ni] = mfma16(af[mi][1], b1[ni][1], acc[mi][2+ni]);
      }
    __builtin_amdgcn_s_setprio(0);
    __builtin_amdgcn_sched_barrier(0);
    __builtin_amdgcn_s_barrier();
    // ---- phase 2
    STAGE(ktn, 2, d^1);
    #pragma unroll
    for (int mi = 0; mi < 4; ++mi) {
      int r = wr*128 + (4+mi)*16 + lo;
      af[mi][0] = *(const short8*)(Ab + r*128 + gk0);
      af[mi][1] = *(const short8*)(Ab + r*128 + gk1);
    }
    __builtin_amdgcn_s_barrier();
    __builtin_amdgcn_s_setprio(1);
    #pragma unroll
    for (int mi = 0; mi < 4; ++mi)
      #pragma unroll
      for (int ni = 0; ni < 2; ++ni) {
        acc[4+mi][2+ni] = mfma16(af[mi][0], b1[ni][0], acc[4+mi][2+ni]);
        acc[4+mi][2+ni] = mfma16(af[mi][1], b1[ni][1], acc[4+mi][2+ni]);
      }
    __builtin_amdgcn_s_setprio(0);
    __builtin_amdgcn_sched_barrier(0);
    __builtin_amdgcn_s_barrier();
    // ---- phase 3
    STAGE(ktn, 3, d^1);
    __builtin_amdgcn_s_barrier();
    __builtin_amdgcn_s_setprio(1);
    #pragma unroll
    for (int mi = 0; mi < 4; ++mi)
      #pragma unroll
      for (int ni = 0; ni < 2; ++ni) {
        acc[4+mi][ni] = mfma16(af[mi][0], b0[ni][0], acc[4+mi][ni]);
        acc[4+mi][ni] = mfma16(af[mi][1], b0[ni][1], acc[4+mi][ni]);
      }
    __builtin_amdgcn_s_setprio(0);
    __builtin_amdgcn_sched_barrier(0);
    __builtin_amdgcn_s_barrier();
  }
  if (MODE == 1) {
    #pragma unroll
    for (int mi = 0; mi < 8; ++mi)
      #pragma unroll
      for (int k = 0; k < 2; ++k)
        #pragma unroll
        for (int r = 0; r < 4; ++r) {
          float h1 = acc[mi][2*k][r], h3 = acc[mi][2*k+1][r];
          float sv = h1 / (1.f + __expf(-h1)) * h3;
          int row = m0 + wr*128 + mi*16 + hi*4 + r;
          int col = (n0 >> 1) + wc*32 + k*16 + lo;
          st_out(C + (long)row * ldc + col, sv);
        }
    return;
  }
  if (MODE == 2) {
    int xt = n0 / 3072, rem = n0 - xt*3072;
    if (rem >= 2048 && (xt == 0 || xt == 3)) {
      const int xc = xt ? 1 : 0;
      const int b = m0 >> 8;
      #pragma unroll
      for (int mi = 0; mi < 8; ++mi)
        #pragma unroll
        for (int ni = 0; ni < 4; ++ni) {
          int col = n0 + wc*64 + ni*16 + lo;
          int hd = col - xt*3072 - 2048;
          int h = hd >> 6, dd = hd & 63;
          int trow = wr*128 + mi*16 + hi*4;
          short4v pk;
          #pragma unroll
          for (int r = 0; r < 4; ++r) pk[r] = f2bf(acc[mi][ni][r]);
          *(short4v*)(vtp + ((long)((xc<<8)+(b<<4)+h)*64 + dd)*256 + trow) = pk;
        }
      return;
    }
  }
  #pragma unroll
  for (int mi = 0; mi < 8; ++mi)
    #pragma unroll
    for (int ni = 0; ni < 4; ++ni)
      #pragma unroll
      for (int r = 0; r < 4; ++r) {
        int row = m0 + wr*128 + mi*16 + hi*4 + r;
        int col = n0 + wc*64 + ni*16 + lo;
        st_out(C + (long)row * ldc + col, acc[mi][ni][r]);
      }
}

// ---------------------------------------------------------------------------
// bf16 GEMM 128x128 (used for the small batched Wof precompute).
// ---------------------------------------------------------------------------
template<typename OUT>
__global__ __launch_bounds__(256)
void gemm_bt(const bf16* __restrict__ A, const bf16* __restrict__ Bt,
             OUT* __restrict__ C, int M, int N, int K,
             int lda, int ldb, int ldc,
             long azs, long bzs, long czs, int zdiv,
             long azs2, long bzs2, long czs2)
{
  const int z1 = blockIdx.z % zdiv, z2 = blockIdx.z / zdiv;
  A  += (long)z1 * azs + (long)z2 * azs2;
  Bt += (long)z1 * bzs + (long)z2 * bzs2;
  C  += (long)z1 * czs + (long)z2 * czs2;
  const int n0 = blockIdx.x * 128;
  const int m0 = blockIdx.y * 128;
  __shared__ short As[128*64];
  __shared__ short Bs[128*64];
  char* AsB = (char*)As;
  char* BsB = (char*)Bs;
  const int t = threadIdx.x;
  const int wid = t >> 6, lane = t & 63, lo = lane & 15, hi = lane >> 4;
  const int wr = wid >> 1, wc = wid & 1;
  const int rst  = t >> 3;
  const int glog = (t & 7) ^ (rst & 7);
  const int ldsbase = wid * 1024;
  f32x4 acc[4][4] = {};
  const bf16* Ap = A + (long)m0 * lda + glog * 8;
  const bf16* Bp = Bt + (long)n0 * ldb + glog * 8;
  const int nkt = K >> 6;
  for (int kt = 0; kt < nkt; ++kt) {
    const long ko = (long)kt * 64;
    #pragma unroll
    for (int i = 0; i < 4; ++i)
      gll16(Ap + (long)(i*32 + rst) * lda + ko, AsB + i*4096 + ldsbase);
    #pragma unroll
    for (int i = 0; i < 4; ++i)
      gll16(Bp + (long)(i*32 + rst) * ldb + ko, BsB + i*4096 + ldsbase);
    __syncthreads();
    #pragma unroll
    for (int kk = 0; kk < 2; ++kk) {
      const int g = ((kk*4 + hi) ^ (lo & 7)) << 4;
      short8 af[4], bfv[4];
      #pragma unroll
      for (int mi = 0; mi < 4; ++mi) {
        int r = wr*64 + mi*16 + lo;
        af[mi] = *(const short8*)(AsB + r*128 + g);
      }
      #pragma unroll
      for (int ni = 0; ni < 4; ++ni) {
        int r = wc*64 + ni*16 + lo;
        bfv[ni] = *(const short8*)(BsB + r*128 + g);
      }
      #pragma unroll
      for (int mi = 0; mi < 4; ++mi)
        #pragma unroll
        for (int ni = 0; ni < 4; ++ni)
          acc[mi][ni] = mfma16(af[mi], bfv[ni], acc[mi][ni]);
    }
    __syncthreads();
  }
  #pragma unroll
  for (int mi = 0; mi < 4; ++mi)
    #pragma unroll
    for (int ni = 0; ni < 4; ++ni)
      #pragma unroll
      for (int r = 0; r < 4; ++r) {
        int row = m0 + wr*64 + mi*16 + hi*4 + r;
        int col = n0 + wc*64 + ni*16 + lo;
        st_out(C + (long)row * ldc + col, acc[mi][ni][r]);
      }
}

// ---------------------------------------------------------------------------
// Flash attention for branches {0,3}, FLAT softmax. grid: (256 bh, 2 xc).
// ---------------------------------------------------------------------------
__global__ __launch_bounds__(256)
void attn_k(const bf16* __restrict__ qkv, const bf16* __restrict__ vt,
            bf16* __restrict__ ctx)
{
  const int xc = blockIdx.y;
  const int x = xc * 3;
  const int bh = blockIdx.x;
  const int b = bh >> 4, h = bh & 15;
  const int t = threadIdx.x, wid = t >> 6, lane = t & 63;
  const int lo = lane & 15, hi = lane >> 4;
  const int q0 = wid * 64;
  const float bsc = (xc == 0) ? -0.05f : 0.0f;
  __shared__ short Pl[4][64*64];
  char* P = (char*)Pl[wid];
  const bf16* qb = qkv + (long)(b*SS) * 12288 + x*3072 + h*64;
  const bf16* kb = qb + 1024;
  const bf16* vb = vt + (long)(xc*256 + b*16 + h) * 64 * 256;

  short8 qf[4][2];
  #pragma unroll
  for (int mi = 0; mi < 4; ++mi)
    #pragma unroll
    for (int kk = 0; kk < 2; ++kk)
      qf[mi][kk] = *(const short8*)(qb + (long)(q0 + mi*16 + lo) * 12288 + kk*32 + hi*8);

  float sr[4][4];
  f32x4 aco[4][4] = {};
  #pragma unroll
  for (int i = 0; i < 4; ++i)
    #pragma unroll
    for (int r = 0; r < 4; ++r) sr[i][r] = 0.f;

  for (int c = 0; c < 4; ++c) {
    f32x4 acc[4][4] = {};
    #pragma unroll
    for (int kk = 0; kk < 2; ++kk) {
      short8 bfv[4];
      #pragma unroll
      for (int ni = 0; ni < 4; ++ni)
        bfv[ni] = *(const short8*)(kb + (long)(c*64 + ni*16 + lo) * 12288 + kk*32 + hi*8);
      #pragma unroll
      for (int mi = 0; mi < 4; ++mi)
        #pragma unroll
        for (int ni = 0; ni < 4; ++ni)
          acc[mi][ni] = mfma16(qf[mi][kk], bfv[ni], acc[mi][ni]);
    }
    // flat softmax numerator: P = exp(s/8 + bias), accumulate row sums
    #pragma unroll
    for (int mi = 0; mi < 4; ++mi)
      #pragma unroll
      for (int ni = 0; ni < 4; ++ni)
        #pragma unroll
        for (int r = 0; r < 4; ++r) {
          int lqq = mi*16 + hi*4 + r;          // local q row in wave tile
          int qq = q0 + lqq;                   // global q row
          int ttl = ni*16 + lo;                // LOCAL col within chunk
          int tt = c*64 + ttl;                 // global col (bias only)
          float s = fmaf(fabsf((float)(qq - tt)), bsc, acc[mi][ni][r] * 0.125f);
          float pv = __expf(s);
          sr[mi][r] += pv;
          int gph = ((ttl >> 3) ^ (lqq & 7)) << 4;
          *(bf16*)(P + lqq*128 + gph + (ttl & 7)*2) = __float2bfloat16(pv);
        }
    // PV
    #pragma unroll
    for (int kk = 0; kk < 2; ++kk) {
      short8 pf[4], vf[4];
      #pragma unroll
      for (int mi = 0; mi < 4; ++mi) {
        int qq = mi*16 + lo;
        int gph = ((kk*4 + hi) ^ (qq & 7)) << 4;
        pf[mi] = *(const short8*)(P + qq*128 + gph);
      }
      #pragma unroll
      for (int di = 0; di < 4; ++di)
        vf[di] = *(const short8*)(vb + (long)(di*16 + lo) * 256 + c*64 + kk*32 + hi*8);
      #pragma unroll
      for (int mi = 0; mi < 4; ++mi)
        #pragma unroll
        for (int di = 0; di < 4; ++di)
          aco[mi][di] = mfma16(pf[mi], vf[di], aco[mi][di]);
    }
  }
  // final row-sum reduce and write ctx (K-concat layout, ld=4096)
  #pragma unroll
  for (int mi = 0; mi < 4; ++mi)
    #pragma unroll
    for (int r = 0; r < 4; ++r) {
      float s = sr[mi][r];
      #pragma unroll
      for (int d = 1; d < 16; d <<= 1) s += __shfl_xor(s, d);
      sr[mi][r] = s;
    }
  bf16* cb = ctx + (long)(b*SS) * 4096 + x*1024 + h*64;
  #pragma unroll
  for (int mi = 0; mi < 4; ++mi)
    #pragma unroll
    for (int di = 0; di < 4; ++di)
      #pragma unroll
      for (int r = 0; r < 4; ++r) {
        int row = q0 + mi*16 + hi*4 + r;
        int col = di*16 + lo;
        cb[(long)row * 4096 + col] = __float2bfloat16(aco[mi][di][r] / sr[mi][r]);
      }
}

// ---------------------------------------------------------------------------
// Branches 1 (chain) and 2 (pair), flat softmax (boundary masks -> exp -> 0).
// grid: (B*S = 4096); wave = head-group (4 heads each) for one token.
// ---------------------------------------------------------------------------
__global__ __launch_bounds__(256)
void br12_k(const bf16* __restrict__ qkv, bf16* __restrict__ ctx)
{
  const unsigned short* Q = (const unsigned short*)qkv;
  const int wid = threadIdx.x >> 6, lane = threadIdx.x & 63;
  const int b = blockIdx.x >> 8, i = blockIdx.x & 255;
  const long rowQ = (long)(b*SS + i) * 12288;
  const long rb = (long)(b*SS) * 12288;
  const int jm = i > 0 ? i-1 : 0;
  const int jp = i < SS-1 ? i+1 : SS-1;
  const int j0 = i & ~1, j1 = j0 | 1;
  unsigned short* outp = (unsigned short*)ctx + (long)(b*SS + i) * 4096;
  #pragma unroll
  for (int hh = 0; hh < 4; ++hh) {
    const int h = wid*4 + hh;
    const int off1 = 3072 + h*64 + lane;
    const int off2 = 6144 + h*64 + lane;
    float q1d = bf2f(Q[rowQ + off1]);
    float q2d = bf2f(Q[rowQ + off2]);
    float km = bf2f(Q[rb + (long)jm*12288 + off1 + 1024]);
    float k0 = bf2f(Q[rb + (long)i *12288 + off1 + 1024]);
    float kp = bf2f(Q[rb + (long)jp*12288 + off1 + 1024]);
    float ka = bf2f(Q[rb + (long)j0*12288 + off2 + 1024]);
    float kb_ = bf2f(Q[rb + (long)j1*12288 + off2 + 1024]);
    float s0 = q1d*km, s1 = q1d*k0, s2 = q1d*kp, s3 = q2d*ka, s4 = q2d*kb_;
    #pragma unroll
    for (int st = 1; st < 64; st <<= 1) {
      s0 += __shfl_xor(s0, st); s1 += __shfl_xor(s1, st); s2 += __shfl_xor(s2, st);
      s3 += __shfl_xor(s3, st); s4 += __shfl_xor(s4, st);
    }
    float lm = s0*0.125f + (i > 0      ? 0.f : -1e30f);
    float l0 = s1*0.125f;
    float lp = s2*0.125f + (i < SS-1   ? 0.f : -1e30f);
    float pm = __expf(lm), p0 = __expf(l0), pp = __expf(lp);
    float vm = bf2f(Q[rb + (long)jm*12288 + off1 + 2048]);
    float v0 = bf2f(Q[rb + (long)i *12288 + off1 + 2048]);
    float vp = bf2f(Q[rb + (long)jp*12288 + off1 + 2048]);
    float o1 = (pm*vm + p0*v0 + pp*vp) / (pm+p0+pp);
    float la = s3*0.125f, lb = s4*0.125f;
    float pa = __expf(la), pb = __expf(lb);
    float va = bf2f(Q[rb + (long)j0*12288 + off2 + 2048]);
    float vb2= bf2f(Q[rb + (long)j1*12288 + off2 + 2048]);
    float o2 = (pa*va + pb*vb2) / (pa+pb);
    outp[1024 + h*64 + lane] = (unsigned short)f2bf(o1);
    outp[2048 + h*64 + lane] = (unsigned short)f2bf(o2);
  }
}

// ---------------------------------------------------------------------------
// Fused residual + LayerNorm + adaLN modulation.
//   v = xin + gate*(sum_{j<ycnt} y_j + ybias)   (y: bf16 partials; null => v=xin)
// ---------------------------------------------------------------------------
__global__ __launch_bounds__(256)
void ln_fused(const float* __restrict__ xin, const bf16* __restrict__ y,
              int ycnt, long ystride,
              const float* __restrict__ ybias, const float* __restrict__ gate,
              const float* __restrict__ lnw, const float* __restrict__ lnb,
              const float* __restrict__ sc, const float* __restrict__ sh,
              float* __restrict__ xout, bf16* __restrict__ xnbf,
              float* __restrict__ xnf)
{
  int row = blockIdx.x;
  int b = row >> 8;
  int t = threadIdx.x;
  int d0 = t * 4;
  const float* xr = xin + (long)row * DD;
  f32x4 xi = *(const f32x4*)(xr + d0);
  float v[4];
  if (y) {
    f32x4 ys = {};
    for (int jp = 0; jp < ycnt; ++jp) {
      short4v yv = *(const short4v*)(y + jp*ystride + (long)row * DD + d0);
      #pragma unroll
      for (int j = 0; j < 4; ++j) ys[j] += bf2f(yv[j]);
    }
    #pragma unroll
    for (int j = 0; j < 4; ++j) {
      float yy = ys[j] + (ybias ? ybias[d0+j] : 0.f);
      v[j] = xi[j] + gate[b*6144 + d0 + j] * yy;
    }
  } else {
    #pragma unroll
    for (int j = 0; j < 4; ++j) v[j] = xi[j];
  }
  if (xout) {
    f32x4 o; o[0]=v[0]; o[1]=v[1]; o[2]=v[2]; o[3]=v[3];
    *(f32x4*)(xout + (long)row * DD + d0) = o;
  }
  float s = v[0]+v[1]+v[2]+v[3];
  float s2 = v[0]*v[0]+v[1]*v[1]+v[2]*v[2]+v[3]*v[3];
  #pragma unroll
  for (int d = 1; d < 64; d <<= 1) { s += __shfl_xor(s, d); s2 += __shfl_xor(s2, d); }
  __shared__ float rs[4][2];
  int wid = t >> 6, lane = t & 63;
  if (lane == 0) { rs[wid][0] = s; rs[wid][1] = s2; }
  __syncthreads();
  s  = rs[0][0]+rs[1][0]+rs[2][0]+rs[3][0];
  s2 = rs[0][1]+rs[1][1]+rs[2][1]+rs[3][1];
  float mean = s * (1.f/1024.f);
  float var  = s2 * (1.f/1024.f) - mean*mean;
  float rstd = rsqrtf(var + 1e-6f);
  #pragma unroll
  for (int j = 0; j < 4; ++j) {
    int d = d0 + j;
    float xn = (v[j] - mean) * rstd * lnw[d] + lnb[d];
    if (sc) {
      float val = xn * (1.f + sc[b*6144 + d]) + sh[b*6144 + d];
      xnbf[(long)row * DD + d] = __float2bfloat16(val);
    } else if (xnbf) {
      xnbf[(long)row * DD + d] = __float2bfloat16(xn);
    } else {
      xnf[(long)row * DD + d] = xn;
    }
  }
}

// ---------------------------------------------------------------------------
// adaLN: fused silu(t_emb) + split-K partial GEMM, then reduce.
// a_gemm grid: (6 nblk, 8 kc, 6 l)
// ---------------------------------------------------------------------------
__global__ __launch_bounds__(256)
void a_gemm(const float* __restrict__ Wa, const float* __restrict__ te,
            float* __restrict__ partial)
{
  int l = blockIdx.z, kc = blockIdx.y;
  int n0 = (blockIdx.x * 256 + threadIdx.x) * 4;
  __shared__ float sl[16*128];
  for (int i = threadIdx.x; i < 16*128; i += 256) {
    int m = i >> 7, k = i & 127;
    float v = te[m*1024 + kc*128 + k];
    sl[i] = v / (1.f + __expf(-v));        // fused SiLU
  }
  __syncthreads();
  f32x4 acc[16] = {};
  const float* wp = Wa + (long)l * DD * 6144 + (long)(kc*128) * 6144 + n0;
  #pragma unroll 4
  for (int k = 0; k < 128; ++k) {
    f32x4 w = *(const f32x4*)(wp + (long)k * 6144);
    #pragma unroll
    for (int m = 0; m < 16; ++m) {
      float sv = sl[m*128 + k];
      #pragma unroll
      for (int j = 0; j < 4; ++j) acc[m][j] += sv * w[j];
    }
  }
  #pragma unroll
  for (int m = 0; m < 16; ++m)
    *(f32x4*)(partial + ((long)(l*8 + kc)*16 + m) * 6144 + n0) = acc[m];
}

__global__ __launch_bounds__(256)
void a_red(const float* __restrict__ partial, const float* __restrict__ ba,
           float* __restrict__ a_all)
{
  int idx = blockIdx.x * 256 + threadIdx.x;
  int n = idx % 6144;
  int lm = idx / 6144;
  int l = lm >> 4, m = lm & 15;
  float s = 0.f;
  #pragma unroll
  for (int kc = 0; kc < 8; ++kc)
    s += partial[((long)(l*8 + kc)*16 + m) * 6144 + n];
  a_all[(long)(l*16 + m) * 6144 + n] = s + ba[(long)l * 6144 + n];
}

// ---------------------------------------------------------------------------
// Final projection
// ---------------------------------------------------------------------------
__global__ __launch_bounds__(256)
void proj_k(const float* __restrict__ xnf, const float* __restrict__ Wp,
            const float* __restrict__ bp, float* __restrict__ out)
{
  int v = threadIdx.x & 31, tg = threadIdx.x >> 5;
  int s = blockIdx.x * 8 + tg;
  const float* xr = xnf + (long)s * DD;
  float acc = bp[v];
  #pragma unroll 8
  for (int k = 0; k < DD; ++k) acc += xr[k] * Wp[(long)k * VV + v];
  out[(long)s * VV + v] = acc;
}

// ---------------------------------------------------------------------------
extern "C" void kernel_launch(void* const* d_in, const int* in_sizes, int n_in,
                              void* d_out, int out_size, void* d_ws, size_t ws_size,
                              hipStream_t stream)
{
  (void)in_sizes; (void)n_in; (void)out_size; (void)ws_size;
  const float* x_in = (const float*)d_in[0];
  const float* t_emb= (const float*)d_in[1];
  const float* ln1w = (const float*)d_in[2];
  const float* ln1b = (const float*)d_in[3];
  const float* ln2w = (const float*)d_in[4];
  const float* ln2b = (const float*)d_in[5];
  const float* Wqkv = (const float*)d_in[6];
  const float* Wo   = (const float*)d_in[7];
  const float* Wf   = (const float*)d_in[8];
  const float* bfb  = (const float*)d_in[9];
  const float* W1   = (const float*)d_in[10];
  const float* W3   = (const float*)d_in[11];
  const float* W2   = (const float*)d_in[12];
  const float* Wa   = (const float*)d_in[13];
  const float* ba   = (const float*)d_in[14];
  const float* fnw  = (const float*)d_in[15];
  const float* fnb  = (const float*)d_in[16];
  const float* Wp   = (const float*)d_in[17];
  const float* bp   = (const float*)d_in[18];
  float* out = (float*)d_out;

  char* p = (char*)d_ws;
  auto alloc = [&](size_t bytes) { char* r = p; p += (bytes + 255) & ~(size_t)255; return r; };
  bf16* wqkv_t = (bf16*)alloc(6L*4*3072*1024*2);
  bf16* wo_b   = (bf16*)alloc(6L*4*1024*1024*2);
  bf16* wf_t   = (bf16*)alloc(6L*1024*4096*2);
  bf16* wof_t  = (bf16*)alloc(6L*1024*4096*2);
  bf16* w13i_t = (bf16*)alloc(6L*8192*1024*2);
  bf16* w2_t   = (bf16*)alloc(6L*1024*4096*2);
  float* a_all = (float*)alloc(6L*16*6144*4);
  float* a_par = (float*)alloc(6L*8*16*6144*4);
  float* x_buf = (float*)alloc((long)MM*DD*4);
  bf16* xn     = (bf16*)alloc((long)MM*DD*2);
  char* bufA   = alloc((long)MM*12288*2);          // qkv
  bf16* vt     = (bf16*)alloc(2L*16*16*64*256*2);
  bf16* ctx    = (bf16*)alloc((long)MM*4096*2);    // K-concat layout
  char* bufB   = alloc((long)MM*4096*2);           // hg | xnf(fp32)
  bf16* gy     = (bf16*)alloc(4L*MM*DD*2);         // 4 bf16 split-K partials

  bf16* qkvb = (bf16*)bufA;
  bf16* hg   = (bf16*)bufB;
  float* xnf = (float*)bufB;
  const long MMDD = (long)MM*DD;

  // --- upfront: adaLN + ALL weight conversions (batched across layers) ---
  a_gemm<<<dim3(6, 8, 6), 256, 0, stream>>>(Wa, t_emb, a_par);
  a_red<<<dim3(2304), 256, 0, stream>>>(a_par, ba, a_all);
  tcvt64<<<dim3(48,16,24),256,0,stream>>>(Wqkv, wqkv_t, 1024, 3072, 1024L*3072, 3072L*1024);
  cvt<<<dim3(12288),256,0,stream>>>(Wo, wo_b);
  tcvt64<<<dim3(16,64,6),256,0,stream>>>(Wf, wf_t, 4096, 1024, 4096L*1024, 4096L*1024);
  tcvt64_w13<<<dim3(64,16,12),256,0,stream>>>(W1, W3, w13i_t);
  tcvt64<<<dim3(16,64,6),256,0,stream>>>(W2, w2_t, 4096, 1024, 4096L*1024, 4096L*1024);
  // Wof[l][x] = Wo_lx @ Wf_lx-block (stored transposed): z = l*4 + x
  gemm_bt<bf16><<<dim3(8,8,24),256,0,stream>>>(wf_t, wo_b, wof_t,
      1024, 1024, 1024, 4096, 1024, 4096,
      1024L, 1024L*1024, 1024L, 4,
      1024L*4096, 4L*1024*1024, 1024L*4096);

  const long aL = 16L * 6144;
  ln_fused<<<4096,256,0,stream>>>(x_in, nullptr, 0, 0, nullptr, nullptr,
                                  ln1w, ln1b, a_all+1024, a_all+0,
                                  nullptr, xn, nullptr);

  for (int l = 0; l < LL; ++l) {
    const float* a_l = a_all + (long)l * aL;
    // QKV with fused V-transpose for branches 0/3
    gemm256<bf16,2><<<dim3(48,16,1),512,0,stream>>>(xn, wqkv_t + (long)l*4*3072*1024,
        qkvb, 1024, 1024, 1024, 12288, 0, 0, 1, vt);
    attn_k<<<dim3(256,2),256,0,stream>>>(qkvb, vt, ctx);
    br12_k<<<dim3(4096),256,0,stream>>>(qkvb, ctx);
    // gy[z] = ctx @ Wof (split-K=4, bf16 partials)
    gemm256<bf16,0><<<dim3(4,16,4),512,0,stream>>>(ctx, wof_t + (long)l*1024*4096,
        gy, 1024, 4096, 4096, 1024, 1024L, MMDD, 1, nullptr);
    ln_fused<<<4096,256,0,stream>>>(l ? x_buf : x_in, gy, 4, MMDD,
                                    bfb + (long)l*1024, a_l+2048,
                                    ln2w + (long)l*1024, ln2b + (long)l*1024,
                                    a_l+4096, a_l+3072, x_buf, xn, nullptr);
    // hg = swiglu(xn @ W13) fused
    gemm256<bf16,1><<<dim3(32,16,1),512,0,stream>>>(xn, w13i_t + (long)l*8192*1024,
        hg, 1024, 1024, 1024, 4096, 0, 0, 1, nullptr);
    // gy[z] = hg @ W2 (split-K=4, bf16 partials)
    gemm256<bf16,0><<<dim3(4,16,4),512,0,stream>>>(hg, w2_t + (long)l*1024*4096,
        gy, 1024, 4096, 4096, 1024, 1024L, MMDD, 1, nullptr);
    if (l < LL-1)
      ln_fused<<<4096,256,0,stream>>>(x_buf, gy, 4, MMDD, nullptr, a_l+5120,
                                      ln1w + (long)(l+1)*1024, ln1b + (long)(l+1)*1024,
                                      a_all + (long)(l+1)*aL + 1024, a_all + (long)(l+1)*aL,
                                      x_buf, xn, nullptr);
    else
      ln_fused<<<4096,256,0,stream>>>(x_buf, gy, 4, MMDD, nullptr, a_l+5120,
                                      fnw, fnb, nullptr, nullptr,
                                      x_buf, nullptr, xnf);
  }
  proj_k<<<dim3(512),256,0,stream>>>(xnf, Wp, bp, out);
}

// Round 12
// 2783.410 us; speedup vs baseline: 1.0497x; 1.0166x over previous
//
#include <hip/hip_runtime.h>
#include <hip/hip_bf16.h>
#include <math.h>

// Problem constants
#define BB 16
#define SS 256
#define DD 1024
#define HH 16
#define HDD 64
#define FF 4096
#define LL 6
#define VV 32
#define MM (BB*SS)   // 4096 tokens

using bf16 = __hip_bfloat16;
using short4v = __attribute__((ext_vector_type(4))) short;
using short8 = __attribute__((ext_vector_type(8))) short;
using f32x4  = __attribute__((ext_vector_type(4))) float;

__device__ __forceinline__ float bf2f(short u){
  unsigned int x = ((unsigned int)(unsigned short)u) << 16;
  return __builtin_bit_cast(float, x);
}
__device__ __forceinline__ short f2bf(float f){
  return __builtin_bit_cast(short, __float2bfloat16(f));
}

__device__ __forceinline__ void gll16(const void* g, void* l) {
  __builtin_amdgcn_global_load_lds(
      (const __attribute__((address_space(1))) void*)g,
      (__attribute__((address_space(3))) void*)l,
      16, 0, 0);
}

__device__ __forceinline__ f32x4 mfma16(short8 a, short8 b, f32x4 c){
  return __builtin_amdgcn_mfma_f32_16x16x32_bf16(a, b, c, 0, 0, 0);
}

__device__ __forceinline__ void st_out(float* p, float v){ *p = v; }
__device__ __forceinline__ void st_out(bf16* p, float v){ *p = __float2bfloat16(v); }

// ---------------------------------------------------------------------------
// Tiled transpose + fp32->bf16 convert: in [R][C] fp32 -> out [C][R] bf16.
// ---------------------------------------------------------------------------
__global__ __launch_bounds__(256)
void tcvt64(const float* __restrict__ in, bf16* __restrict__ out,
            int R, int C, long izs, long ozs)
{
  in  += (long)blockIdx.z * izs;
  out += (long)blockIdx.z * ozs;
  __shared__ float tl[64][65];
  int c0 = blockIdx.x * 64, r0 = blockIdx.y * 64;
  int t = threadIdx.x;
  int tr = t >> 4, tc = (t & 15) * 4;
  #pragma unroll
  for (int i = 0; i < 4; ++i) {
    f32x4 v = *(const f32x4*)(in + (long)(r0 + tr + i*16) * C + c0 + tc);
    tl[tr + i*16][tc+0] = v[0];
    tl[tr + i*16][tc+1] = v[1];
    tl[tr + i*16][tc+2] = v[2];
    tl[tr + i*16][tc+3] = v[3];
  }
  __syncthreads();
  int oc = t >> 2, rch = (t & 3) * 16;
  short8 o0, o1;
  #pragma unroll
  for (int j = 0; j < 8; ++j) o0[j] = f2bf(tl[rch + j][oc]);
  #pragma unroll
  for (int j = 0; j < 8; ++j) o1[j] = f2bf(tl[rch + 8 + j][oc]);
  *(short8*)(out + (long)(c0 + oc) * R + r0 + rch)     = o0;
  *(short8*)(out + (long)(c0 + oc) * R + r0 + rch + 8) = o1;
}

// W1/W3 transpose+convert, interleaved row remap for fused SwiGLU.
// grid: (64, 16, 12): z = l*2 + (0:W1, 1:W3)
__global__ __launch_bounds__(256)
void tcvt64_w13(const float* __restrict__ W1, const float* __restrict__ W3,
                bf16* __restrict__ out)
{
  int l = blockIdx.z >> 1;
  const float* in = ((blockIdx.z & 1) ? W3 : W1) + (long)l * 1024 * 4096;
  const int zoff = (blockIdx.z & 1) ? 16 : 0;
  bf16* o = out + (long)l * 8192 * 1024;
  __shared__ float tl[64][65];
  int c0 = blockIdx.x * 64, r0 = blockIdx.y * 64;
  int t = threadIdx.x;
  int tr = t >> 4, tc = (t & 15) * 4;
  #pragma unroll
  for (int i = 0; i < 4; ++i) {
    f32x4 v = *(const f32x4*)(in + (long)(r0 + tr + i*16) * 4096 + c0 + tc);
    tl[tr + i*16][tc+0] = v[0];
    tl[tr + i*16][tc+1] = v[1];
    tl[tr + i*16][tc+2] = v[2];
    tl[tr + i*16][tc+3] = v[3];
  }
  __syncthreads();
  int oc = t >> 2, rch = (t & 3) * 16;
  short8 o0, o1;
  #pragma unroll
  for (int j = 0; j < 8; ++j) o0[j] = f2bf(tl[rch + j][oc]);
  #pragma unroll
  for (int j = 0; j < 8; ++j) o1[j] = f2bf(tl[rch + 8 + j][oc]);
  int n = c0 + oc;
  int orow = ((n >> 4) << 5) + zoff + (n & 15);
  *(short8*)(o + (long)orow * 1024 + r0 + rch)     = o0;
  *(short8*)(o + (long)orow * 1024 + r0 + rch + 8) = o1;
}

// plain fp32 -> bf16 convert; 8 elems/thread
__global__ __launch_bounds__(256)
void cvt(const float* __restrict__ in, bf16* __restrict__ out)
{
  long base = ((long)blockIdx.x * 256 + threadIdx.x) * 8;
  f32x4 a = *(const f32x4*)(in + base);
  f32x4 b = *(const f32x4*)(in + base + 4);
  short8 o;
  #pragma unroll
  for (int j = 0; j < 4; ++j) { o[j] = f2bf(a[j]); o[4+j] = f2bf(b[j]); }
  *(short8*)(out + base) = o;
}

// ---------------------------------------------------------------------------
// 256x256-tile 8-phase bf16 GEMM.
// MODE 0: plain store. MODE 1: fused SwiGLU. MODE 2: QKV with fused
//   V-transpose for branches 0/3 (V-tiles write ONLY vt, skip C).
// z decomposed 2-level: z1 = z % zdiv, z2 = z / zdiv with separate strides.
// ---------------------------------------------------------------------------
template<typename OUT, int MODE>
__global__ __launch_bounds__(512, 2)
void gemm256(const bf16* __restrict__ A, const bf16* __restrict__ Bt,
             OUT* __restrict__ C, int K,
             int lda, int ldb, int ldc,
             long az1, long bz1, long cz1, int zdiv,
             long az2, long bz2, long cz2, int swz,
             bf16* __restrict__ vtp)
{
  __shared__ short lds[65536];   // 128 KiB
  char* L = (char*)lds;
  const int z1 = blockIdx.z % zdiv, z2 = blockIdx.z / zdiv;
  A  += (long)z1 * az1 + (long)z2 * az2;
  Bt += (long)z1 * bz1 + (long)z2 * bz2;
  C  += (long)z1 * cz1 + (long)z2 * cz2;
  int lin = blockIdx.x + gridDim.x * blockIdx.y;
  if (swz) {
    int nwg = gridDim.x * gridDim.y;
    int q = nwg >> 3, r = nwg & 7;
    int xcd = lin & 7, o = lin >> 3;
    lin = (xcd < r ? xcd*(q+1) : r*(q+1) + (xcd-r)*q) + o;
  }
  const int n0 = (lin % gridDim.x) * 256;
  const int m0 = (lin / gridDim.x) * 256;
  const int t = threadIdx.x;
  const int wid = t >> 6, lane = t & 63, lo = lane & 15, hi = lane >> 4;
  const int wr = wid >> 2, wc = wid & 3;
  const int rst = t >> 3;
  const int glog = (t & 7) ^ (rst & 7);
  const int wub = wid * 1024;
  const bf16* Ap = A + (long)m0 * lda + glog * 8;
  const bf16* Bp = Bt + (long)n0 * ldb + glog * 8;
  f32x4 acc[8][4] = {};
  const int nkt = K >> 6;

  auto STAGE = [&](int kt, int p, int d) {
    const long ko = (long)kt * 64;
    char* base = L + d*65536;
    if (p < 2) {
      gll16(Ap + (long)((p*2  )*64 + rst)*lda + ko, base + (p*2  )*8192 + wub);
      gll16(Ap + (long)((p*2+1)*64 + rst)*lda + ko, base + (p*2+1)*8192 + wub);
    } else {
      int pp = p - 2;
      gll16(Bp + (long)((pp*2  )*64 + rst)*ldb + ko, base + 32768 + (pp*2  )*8192 + wub);
      gll16(Bp + (long)((pp*2+1)*64 + rst)*ldb + ko, base + 32768 + (pp*2+1)*8192 + wub);
    }
  };

  #pragma unroll
  for (int p = 0; p < 4; ++p) STAGE(0, p, 0);

  short8 af[4][2], b0[2][2], b1[2][2];
  const int gk0 = ((0*4 + hi) ^ (lo & 7)) << 4;
  const int gk1 = ((1*4 + hi) ^ (lo & 7)) << 4;

  for (int kt = 0; kt < nkt; ++kt) {
    const int d = kt & 1;
    const int ktn = (kt+1 < nkt) ? kt+1 : kt;
    char* Ab = L + d*65536;
    char* Bb = Ab + 32768;
    // ---- phase 0
    STAGE(ktn, 0, d^1);
    __builtin_amdgcn_sched_barrier(0);
    asm volatile("s_waitcnt vmcnt(2)" ::: "memory");
    __builtin_amdgcn_sched_barrier(0);
    __builtin_amdgcn_s_barrier();
    __builtin_amdgcn_sched_barrier(0);
    #pragma unroll
    for (int mi = 0; mi < 4; ++mi) {
      int r = wr*128 + mi*16 + lo;
      af[mi][0] = *(const short8*)(Ab + r*128 + gk0);
      af[mi][1] = *(const short8*)(Ab + r*128 + gk1);
    }
    #pragma unroll
    for (int ni = 0; ni < 2; ++ni) {
      int r = wc*64 + ni*16 + lo;
      b0[ni][0] = *(const short8*)(Bb + r*128 + gk0);
      b0[ni][1] = *(const short8*)(Bb + r*128 + gk1);
    }
    __builtin_amdgcn_s_barrier();
    __builtin_amdgcn_s_setprio(1);
    #pragma unroll
    for (int mi = 0; mi < 4; ++mi)
      #pragma unroll
      for (int ni = 0; ni < 2; ++ni) {
        acc[mi][ni] = mfma16(af[mi][0], b0[ni][0], acc[mi][ni]);
        acc[mi][ni] = mfma16(af[mi][1], b0[ni][1], acc[mi][ni]);
      }
    __builtin_amdgcn_s_setprio(0);
    __builtin_amdgcn_sched_barrier(0);
    __builtin_amdgcn_s_barrier();
    // ---- phase 1
    STAGE(ktn, 1, d^1);
    #pragma unroll
    for (int ni = 0; ni < 2; ++ni) {
      int r = wc*64 + (2+ni)*16 + lo;
      b1[ni][0] = *(const short8*)(Bb + r*128 + gk0);
      b1[ni][1] = *(const short8*)(Bb + r*128 + gk1);
    }
    __builtin_amdgcn_s_barrier();
    __builtin_amdgcn_s_setprio(1);
    #pragma unroll
    for (int mi = 0; mi < 4; ++mi)
      #pragma unroll
      for (int ni = 0; ni < 2; ++ni) {
        acc[mi][2+ni] = mfma16(af[mi][0], b1[ni][0], acc[mi][2+ni]);
        acc[mi][2+ni] = mfma16(af[mi][1], b1[ni][1], acc[mi][2+ni]);
      }
    __builtin_amdgcn_s_setprio(0);
    __builtin_amdgcn_sched_barrier(0);
    __builtin_amdgcn_s_barrier();
    // ---- phase 2
    STAGE(ktn, 2, d^1);
    #pragma unroll
    for (int mi = 0; mi < 4; ++mi) {
      int r = wr*128 + (4+mi)*16 + lo;
      af[mi][0] = *(const short8*)(Ab + r*128 + gk0);
      af[mi][1] = *(const short8*)(Ab + r*128 + gk1);
    }
    __builtin_amdgcn_s_barrier();
    __builtin_amdgcn_s_setprio(1);
    #pragma unroll
    for (int mi = 0; mi < 4; ++mi)
      #pragma unroll
      for (int ni = 0; ni < 2; ++ni) {
        acc[4+mi][2+ni] = mfma16(af[mi][0], b1[ni][0], acc[4+mi][2+ni]);
        acc[4+mi][2+ni] = mfma16(af[mi][1], b1[ni][1], acc[4+mi][2+ni]);
      }
    __builtin_amdgcn_s_setprio(0);
    __builtin_amdgcn_sched_barrier(0);
    __builtin_amdgcn_s_barrier();
    // ---- phase 3
    STAGE(ktn, 3, d^1);
    __builtin_amdgcn_s_barrier();
    __builtin_amdgcn_s_setprio(1);
    #pragma unroll
    for (int mi = 0; mi < 4; ++mi)
      #pragma unroll
      for (int ni = 0; ni < 2; ++ni) {
        acc[4+mi][ni] = mfma16(af[mi][0], b0[ni][0], acc[4+mi][ni]);
        acc[4+mi][ni] = mfma16(af[mi][1], b0[ni][1], acc[4+mi][ni]);
      }
    __builtin_amdgcn_s_setprio(0);
    __builtin_amdgcn_sched_barrier(0);
    __builtin_amdgcn_s_barrier();
  }
  if (MODE == 1) {
    #pragma unroll
    for (int mi = 0; mi < 8; ++mi)
      #pragma unroll
      for (int k = 0; k < 2; ++k)
        #pragma unroll
        for (int r = 0; r < 4; ++r) {
          float h1 = acc[mi][2*k][r], h3 = acc[mi][2*k+1][r];
          float sv = h1 / (1.f + __expf(-h1)) * h3;
          int row = m0 + wr*128 + mi*16 + hi*4 + r;
          int col = (n0 >> 1) + wc*32 + k*16 + lo;
          st_out(C + (long)row * ldc + col, sv);
        }
    return;
  }
  if (MODE == 2) {
    int xt = n0 / 3072, rem = n0 - xt*3072;
    if (rem >= 2048 && (xt == 0 || xt == 3)) {
      const int xc = xt ? 1 : 0;
      const int b = m0 >> 8;
      #pragma unroll
      for (int mi = 0; mi < 8; ++mi)
        #pragma unroll
        for (int ni = 0; ni < 4; ++ni) {
          int col = n0 + wc*64 + ni*16 + lo;
          int hd = col - xt*3072 - 2048;
          int h = hd >> 6, dd = hd & 63;
          int trow = wr*128 + mi*16 + hi*4;
          short4v pk;
          #pragma unroll
          for (int r = 0; r < 4; ++r) pk[r] = f2bf(acc[mi][ni][r]);
          *(short4v*)(vtp + ((long)((xc<<8)+(b<<4)+h)*64 + dd)*256 + trow) = pk;
        }
      return;
    }
  }
  #pragma unroll
  for (int mi = 0; mi < 8; ++mi)
    #pragma unroll
    for (int ni = 0; ni < 4; ++ni)
      #pragma unroll
      for (int r = 0; r < 4; ++r) {
        int row = m0 + wr*128 + mi*16 + hi*4 + r;
        int col = n0 + wc*64 + ni*16 + lo;
        st_out(C + (long)row * ldc + col, acc[mi][ni][r]);
      }
}

// ---------------------------------------------------------------------------
// Flash attention for branches {0,3}, FLAT softmax. grid: (256 bh, 2 xc).
// ---------------------------------------------------------------------------
__global__ __launch_bounds__(256)
void attn_k(const bf16* __restrict__ qkv, const bf16* __restrict__ vt,
            bf16* __restrict__ ctx)
{
  const int xc = blockIdx.y;
  const int x = xc * 3;
  const int bh = blockIdx.x;
  const int b = bh >> 4, h = bh & 15;
  const int t = threadIdx.x, wid = t >> 6, lane = t & 63;
  const int lo = lane & 15, hi = lane >> 4;
  const int q0 = wid * 64;
  const float bsc = (xc == 0) ? -0.05f : 0.0f;
  __shared__ short Pl[4][64*64];
  char* P = (char*)Pl[wid];
  const bf16* qb = qkv + (long)(b*SS) * 12288 + x*3072 + h*64;
  const bf16* kb = qb + 1024;
  const bf16* vb = vt + (long)(xc*256 + b*16 + h) * 64 * 256;

  short8 qf[4][2];
  #pragma unroll
  for (int mi = 0; mi < 4; ++mi)
    #pragma unroll
    for (int kk = 0; kk < 2; ++kk)
      qf[mi][kk] = *(const short8*)(qb + (long)(q0 + mi*16 + lo) * 12288 + kk*32 + hi*8);

  float sr[4][4];
  f32x4 aco[4][4] = {};
  #pragma unroll
  for (int i = 0; i < 4; ++i)
    #pragma unroll
    for (int r = 0; r < 4; ++r) sr[i][r] = 0.f;

  for (int c = 0; c < 4; ++c) {
    f32x4 acc[4][4] = {};
    #pragma unroll
    for (int kk = 0; kk < 2; ++kk) {
      short8 bfv[4];
      #pragma unroll
      for (int ni = 0; ni < 4; ++ni)
        bfv[ni] = *(const short8*)(kb + (long)(c*64 + ni*16 + lo) * 12288 + kk*32 + hi*8);
      #pragma unroll
      for (int mi = 0; mi < 4; ++mi)
        #pragma unroll
        for (int ni = 0; ni < 4; ++ni)
          acc[mi][ni] = mfma16(qf[mi][kk], bfv[ni], acc[mi][ni]);
    }
    // flat softmax numerator: P = exp(s/8 + bias), accumulate row sums
    #pragma unroll
    for (int mi = 0; mi < 4; ++mi)
      #pragma unroll
      for (int ni = 0; ni < 4; ++ni)
        #pragma unroll
        for (int r = 0; r < 4; ++r) {
          int lqq = mi*16 + hi*4 + r;
          int qq = q0 + lqq;
          int ttl = ni*16 + lo;
          int tt = c*64 + ttl;
          float s = fmaf(fabsf((float)(qq - tt)), bsc, acc[mi][ni][r] * 0.125f);
          float pv = __expf(s);
          sr[mi][r] += pv;
          int gph = ((ttl >> 3) ^ (lqq & 7)) << 4;
          *(bf16*)(P + lqq*128 + gph + (ttl & 7)*2) = __float2bfloat16(pv);
        }
    // PV
    #pragma unroll
    for (int kk = 0; kk < 2; ++kk) {
      short8 pf[4], vf[4];
      #pragma unroll
      for (int mi = 0; mi < 4; ++mi) {
        int qq = mi*16 + lo;
        int gph = ((kk*4 + hi) ^ (qq & 7)) << 4;
        pf[mi] = *(const short8*)(P + qq*128 + gph);
      }
      #pragma unroll
      for (int di = 0; di < 4; ++di)
        vf[di] = *(const short8*)(vb + (long)(di*16 + lo) * 256 + c*64 + kk*32 + hi*8);
      #pragma unroll
      for (int mi = 0; mi < 4; ++mi)
        #pragma unroll
        for (int di = 0; di < 4; ++di)
          aco[mi][di] = mfma16(pf[mi], vf[di], aco[mi][di]);
    }
  }
  #pragma unroll
  for (int mi = 0; mi < 4; ++mi)
    #pragma unroll
    for (int r = 0; r < 4; ++r) {
      float s = sr[mi][r];
      #pragma unroll
      for (int d = 1; d < 16; d <<= 1) s += __shfl_xor(s, d);
      sr[mi][r] = s;
    }
  bf16* cb = ctx + (long)(b*SS) * 4096 + x*1024 + h*64;
  #pragma unroll
  for (int mi = 0; mi < 4; ++mi)
    #pragma unroll
    for (int di = 0; di < 4; ++di)
      #pragma unroll
      for (int r = 0; r < 4; ++r) {
        int row = q0 + mi*16 + hi*4 + r;
        int col = di*16 + lo;
        cb[(long)row * 4096 + col] = __float2bfloat16(aco[mi][di][r] / sr[mi][r]);
      }
}

// ---------------------------------------------------------------------------
// Branches 1 (chain) and 2 (pair), flat softmax.
// grid: (B*S = 4096); wave = head-group (4 heads each) for one token.
// ---------------------------------------------------------------------------
__global__ __launch_bounds__(256)
void br12_k(const bf16* __restrict__ qkv, bf16* __restrict__ ctx)
{
  const unsigned short* Q = (const unsigned short*)qkv;
  const int wid = threadIdx.x >> 6, lane = threadIdx.x & 63;
  const int b = blockIdx.x >> 8, i = blockIdx.x & 255;
  const long rowQ = (long)(b*SS + i) * 12288;
  const long rb = (long)(b*SS) * 12288;
  const int jm = i > 0 ? i-1 : 0;
  const int jp = i < SS-1 ? i+1 : SS-1;
  const int j0 = i & ~1, j1 = j0 | 1;
  unsigned short* outp = (unsigned short*)ctx + (long)(b*SS + i) * 4096;
  #pragma unroll
  for (int hh = 0; hh < 4; ++hh) {
    const int h = wid*4 + hh;
    const int off1 = 3072 + h*64 + lane;
    const int off2 = 6144 + h*64 + lane;
    float q1d = bf2f(Q[rowQ + off1]);
    float q2d = bf2f(Q[rowQ + off2]);
    float km = bf2f(Q[rb + (long)jm*12288 + off1 + 1024]);
    float k0 = bf2f(Q[rb + (long)i *12288 + off1 + 1024]);
    float kp = bf2f(Q[rb + (long)jp*12288 + off1 + 1024]);
    float ka = bf2f(Q[rb + (long)j0*12288 + off2 + 1024]);
    float kb_ = bf2f(Q[rb + (long)j1*12288 + off2 + 1024]);
    float s0 = q1d*km, s1 = q1d*k0, s2 = q1d*kp, s3 = q2d*ka, s4 = q2d*kb_;
    #pragma unroll
    for (int st = 1; st < 64; st <<= 1) {
      s0 += __shfl_xor(s0, st); s1 += __shfl_xor(s1, st); s2 += __shfl_xor(s2, st);
      s3 += __shfl_xor(s3, st); s4 += __shfl_xor(s4, st);
    }
    float lm = s0*0.125f + (i > 0      ? 0.f : -1e30f);
    float l0 = s1*0.125f;
    float lp = s2*0.125f + (i < SS-1   ? 0.f : -1e30f);
    float pm = __expf(lm), p0 = __expf(l0), pp = __expf(lp);
    float vm = bf2f(Q[rb + (long)jm*12288 + off1 + 2048]);
    float v0 = bf2f(Q[rb + (long)i *12288 + off1 + 2048]);
    float vp = bf2f(Q[rb + (long)jp*12288 + off1 + 2048]);
    float o1 = (pm*vm + p0*v0 + pp*vp) / (pm+p0+pp);
    float la = s3*0.125f, lb = s4*0.125f;
    float pa = __expf(la), pb = __expf(lb);
    float va = bf2f(Q[rb + (long)j0*12288 + off2 + 2048]);
    float vb2= bf2f(Q[rb + (long)j1*12288 + off2 + 2048]);
    float o2 = (pa*va + pb*vb2) / (pa+pb);
    outp[1024 + h*64 + lane] = (unsigned short)f2bf(o1);
    outp[2048 + h*64 + lane] = (unsigned short)f2bf(o2);
  }
}

// ---------------------------------------------------------------------------
// Fused residual + LayerNorm + adaLN modulation.
// ---------------------------------------------------------------------------
__global__ __launch_bounds__(256)
void ln_fused(const float* __restrict__ xin, const bf16* __restrict__ y,
              int ycnt, long ystride,
              const float* __restrict__ ybias, const float* __restrict__ gate,
              const float* __restrict__ lnw, const float* __restrict__ lnb,
              const float* __restrict__ sc, const float* __restrict__ sh,
              float* __restrict__ xout, bf16* __restrict__ xnbf,
              float* __restrict__ xnf)
{
  int row = blockIdx.x;
  int b = row >> 8;
  int t = threadIdx.x;
  int d0 = t * 4;
  const float* xr = xin + (long)row * DD;
  f32x4 xi = *(const f32x4*)(xr + d0);
  float v[4];
  if (y) {
    f32x4 ys = {};
    for (int jp = 0; jp < ycnt; ++jp) {
      short4v yv = *(const short4v*)(y + jp*ystride + (long)row * DD + d0);
      #pragma unroll
      for (int j = 0; j < 4; ++j) ys[j] += bf2f(yv[j]);
    }
    #pragma unroll
    for (int j = 0; j < 4; ++j) {
      float yy = ys[j] + (ybias ? ybias[d0+j] : 0.f);
      v[j] = xi[j] + gate[b*6144 + d0 + j] * yy;
    }
  } else {
    #pragma unroll
    for (int j = 0; j < 4; ++j) v[j] = xi[j];
  }
  if (xout) {
    f32x4 o; o[0]=v[0]; o[1]=v[1]; o[2]=v[2]; o[3]=v[3];
    *(f32x4*)(xout + (long)row * DD + d0) = o;
  }
  float s = v[0]+v[1]+v[2]+v[3];
  float s2 = v[0]*v[0]+v[1]*v[1]+v[2]*v[2]+v[3]*v[3];
  #pragma unroll
  for (int d = 1; d < 64; d <<= 1) { s += __shfl_xor(s, d); s2 += __shfl_xor(s2, d); }
  __shared__ float rs[4][2];
  int wid = t >> 6, lane = t & 63;
  if (lane == 0) { rs[wid][0] = s; rs[wid][1] = s2; }
  __syncthreads();
  s  = rs[0][0]+rs[1][0]+rs[2][0]+rs[3][0];
  s2 = rs[0][1]+rs[1][1]+rs[2][1]+rs[3][1];
  float mean = s * (1.f/1024.f);
  float var  = s2 * (1.f/1024.f) - mean*mean;
  float rstd = rsqrtf(var + 1e-6f);
  #pragma unroll
  for (int j = 0; j < 4; ++j) {
    int d = d0 + j;
    float xn = (v[j] - mean) * rstd * lnw[d] + lnb[d];
    if (sc) {
      float val = xn * (1.f + sc[b*6144 + d]) + sh[b*6144 + d];
      xnbf[(long)row * DD + d] = __float2bfloat16(val);
    } else if (xnbf) {
      xnbf[(long)row * DD + d] = __float2bfloat16(xn);
    } else {
      xnf[(long)row * DD + d] = xn;
    }
  }
}

// ---------------------------------------------------------------------------
// adaLN: fused silu(t_emb) + split-K partial GEMM, then reduce.
// ---------------------------------------------------------------------------
__global__ __launch_bounds__(256)
void a_gemm(const float* __restrict__ Wa, const float* __restrict__ te,
            float* __restrict__ partial)
{
  int l = blockIdx.z, kc = blockIdx.y;
  int n0 = (blockIdx.x * 256 + threadIdx.x) * 4;
  __shared__ float sl[16*128];
  for (int i = threadIdx.x; i < 16*128; i += 256) {
    int m = i >> 7, k = i & 127;
    float v = te[m*1024 + kc*128 + k];
    sl[i] = v / (1.f + __expf(-v));        // fused SiLU
  }
  __syncthreads();
  f32x4 acc[16] = {};
  const float* wp = Wa + (long)l * DD * 6144 + (long)(kc*128) * 6144 + n0;
  #pragma unroll 4
  for (int k = 0; k < 128; ++k) {
    f32x4 w = *(const f32x4*)(wp + (long)k * 6144);
    #pragma unroll
    for (int m = 0; m < 16; ++m) {
      float sv = sl[m*128 + k];
      #pragma unroll
      for (int j = 0; j < 4; ++j) acc[m][j] += sv * w[j];
    }
  }
  #pragma unroll
  for (int m = 0; m < 16; ++m)
    *(f32x4*)(partial + ((long)(l*8 + kc)*16 + m) * 6144 + n0) = acc[m];
}

__global__ __launch_bounds__(256)
void a_red(const float* __restrict__ partial, const float* __restrict__ ba,
           float* __restrict__ a_all)
{
  int idx = blockIdx.x * 256 + threadIdx.x;
  int n = idx % 6144;
  int lm = idx / 6144;
  int l = lm >> 4, m = lm & 15;
  float s = 0.f;
  #pragma unroll
  for (int kc = 0; kc < 8; ++kc)
    s += partial[((long)(l*8 + kc)*16 + m) * 6144 + n];
  a_all[(long)(l*16 + m) * 6144 + n] = s + ba[(long)l * 6144 + n];
}

// ---------------------------------------------------------------------------
// Final projection
// ---------------------------------------------------------------------------
__global__ __launch_bounds__(256)
void proj_k(const float* __restrict__ xnf, const float* __restrict__ Wp,
            const float* __restrict__ bp, float* __restrict__ out)
{
  int v = threadIdx.x & 31, tg = threadIdx.x >> 5;
  int s = blockIdx.x * 8 + tg;
  const float* xr = xnf + (long)s * DD;
  float acc = bp[v];
  #pragma unroll 8
  for (int k = 0; k < DD; ++k) acc += xr[k] * Wp[(long)k * VV + v];
  out[(long)s * VV + v] = acc;
}

// ---------------------------------------------------------------------------
extern "C" void kernel_launch(void* const* d_in, const int* in_sizes, int n_in,
                              void* d_out, int out_size, void* d_ws, size_t ws_size,
                              hipStream_t stream)
{
  (void)in_sizes; (void)n_in; (void)out_size; (void)ws_size;
  const float* x_in = (const float*)d_in[0];
  const float* t_emb= (const float*)d_in[1];
  const float* ln1w = (const float*)d_in[2];
  const float* ln1b = (const float*)d_in[3];
  const float* ln2w = (const float*)d_in[4];
  const float* ln2b = (const float*)d_in[5];
  const float* Wqkv = (const float*)d_in[6];
  const float* Wo   = (const float*)d_in[7];
  const float* Wf   = (const float*)d_in[8];
  const float* bfb  = (const float*)d_in[9];
  const float* W1   = (const float*)d_in[10];
  const float* W3   = (const float*)d_in[11];
  const float* W2   = (const float*)d_in[12];
  const float* Wa   = (const float*)d_in[13];
  const float* ba   = (const float*)d_in[14];
  const float* fnw  = (const float*)d_in[15];
  const float* fnb  = (const float*)d_in[16];
  const float* Wp   = (const float*)d_in[17];
  const float* bp   = (const float*)d_in[18];
  float* out = (float*)d_out;

  char* p = (char*)d_ws;
  auto alloc = [&](size_t bytes) { char* r = p; p += (bytes + 255) & ~(size_t)255; return r; };
  bf16* wqkv_t = (bf16*)alloc(6L*4*3072*1024*2);
  bf16* wo_b   = (bf16*)alloc(6L*4*1024*1024*2);
  bf16* wf_t   = (bf16*)alloc(6L*1024*4096*2);
  bf16* wof_t  = (bf16*)alloc(6L*1024*4096*2);
  bf16* w13i_t = (bf16*)alloc(6L*8192*1024*2);
  bf16* w2_t   = (bf16*)alloc(6L*1024*4096*2);
  float* a_all = (float*)alloc(6L*16*6144*4);
  float* a_par = (float*)alloc(6L*8*16*6144*4);
  float* x_buf = (float*)alloc((long)MM*DD*4);
  bf16* xn     = (bf16*)alloc((long)MM*DD*2);
  char* bufA   = alloc((long)MM*12288*2);          // qkv
  bf16* vt     = (bf16*)alloc(2L*16*16*64*256*2);
  bf16* ctx    = (bf16*)alloc((long)MM*4096*2);    // K-concat layout
  char* bufB   = alloc((long)MM*4096*2);           // hg | xnf(fp32)
  bf16* gy     = (bf16*)alloc(4L*MM*DD*2);         // 4 bf16 split-K partials

  bf16* qkvb = (bf16*)bufA;
  bf16* hg   = (bf16*)bufB;
  float* xnf = (float*)bufB;
  const long MMDD = (long)MM*DD;

  // --- upfront: adaLN + ALL weight conversions (batched across layers) ---
  a_gemm<<<dim3(6, 8, 6), 256, 0, stream>>>(Wa, t_emb, a_par);
  a_red<<<dim3(2304), 256, 0, stream>>>(a_par, ba, a_all);
  tcvt64<<<dim3(48,16,24),256,0,stream>>>(Wqkv, wqkv_t, 1024, 3072, 1024L*3072, 3072L*1024);
  cvt<<<dim3(12288),256,0,stream>>>(Wo, wo_b);
  tcvt64<<<dim3(16,64,6),256,0,stream>>>(Wf, wf_t, 4096, 1024, 4096L*1024, 4096L*1024);
  tcvt64_w13<<<dim3(64,16,12),256,0,stream>>>(W1, W3, w13i_t);
  tcvt64<<<dim3(16,64,6),256,0,stream>>>(W2, w2_t, 4096, 1024, 4096L*1024, 4096L*1024);
  // Wof[l][x]: C[n][kk] = sum_j wf_t[l][n][x*1024+j] * wo_b[l][x][kk][j]
  // z = l*4 + x -> z1=x (az1=1024, bz1=1M, cz1=1024), z2=l.
  gemm256<bf16,0><<<dim3(4,4,24),512,0,stream>>>(wf_t, wo_b, wof_t,
      1024, 4096, 1024, 4096,
      1024L, 1024L*1024, 1024L, 4,
      1024L*4096, 4L*1024*1024, 1024L*4096, 0, nullptr);

  const long aL = 16L * 6144;
  ln_fused<<<4096,256,0,stream>>>(x_in, nullptr, 0, 0, nullptr, nullptr,
                                  ln1w, ln1b, a_all+1024, a_all+0,
                                  nullptr, xn, nullptr);

  for (int l = 0; l < LL; ++l) {
    const float* a_l = a_all + (long)l * aL;
    // QKV with fused V-transpose for branches 0/3
    gemm256<bf16,2><<<dim3(48,16,1),512,0,stream>>>(xn, wqkv_t + (long)l*4*3072*1024,
        qkvb, 1024, 1024, 1024, 12288, 0,0,0, 1, 0,0,0, 1, vt);
    attn_k<<<dim3(256,2),256,0,stream>>>(qkvb, vt, ctx);
    br12_k<<<dim3(4096),256,0,stream>>>(qkvb, ctx);
    // gy[z] = ctx @ Wof (split-K=4, bf16 partials)
    gemm256<bf16,0><<<dim3(4,16,4),512,0,stream>>>(ctx, wof_t + (long)l*1024*4096,
        gy, 1024, 4096, 4096, 1024, 1024L, 1024L, MMDD, 4, 0,0,0, 1, nullptr);
    ln_fused<<<4096,256,0,stream>>>(l ? x_buf : x_in, gy, 4, MMDD,
                                    bfb + (long)l*1024, a_l+2048,
                                    ln2w + (long)l*1024, ln2b + (long)l*1024,
                                    a_l+4096, a_l+3072, x_buf, xn, nullptr);
    // hg = swiglu(xn @ W13) fused
    gemm256<bf16,1><<<dim3(32,16,1),512,0,stream>>>(xn, w13i_t + (long)l*8192*1024,
        hg, 1024, 1024, 1024, 4096, 0,0,0, 1, 0,0,0, 1, nullptr);
    // gy[z] = hg @ W2 (split-K=4, bf16 partials)
    gemm256<bf16,0><<<dim3(4,16,4),512,0,stream>>>(hg, w2_t + (long)l*1024*4096,
        gy, 1024, 4096, 4096, 1024, 1024L, 1024L, MMDD, 4, 0,0,0, 1, nullptr);
    if (l < LL-1)
      ln_fused<<<4096,256,0,stream>>>(x_buf, gy, 4, MMDD, nullptr, a_l+5120,
                                      ln1w + (long)(l+1)*1024, ln1b + (long)(l+1)*1024,
                                      a_all + (long)(l+1)*aL + 1024, a_all + (long)(l+1)*aL,
                                      x_buf, xn, nullptr);
    else
      ln_fused<<<4096,256,0,stream>>>(x_buf, gy, 4, MMDD, nullptr, a_l+5120,
                                      fnw, fnb, nullptr, nullptr,
                                      x_buf, nullptr, xnf);
  }
  proj_k<<<dim3(512),256,0,stream>>>(xnf, Wp, bp, out);
}

// Round 13
// 2752.550 us; speedup vs baseline: 1.0615x; 1.0112x over previous
//
#include <hip/hip_runtime.h>
#include <hip/hip_bf16.h>
#include <math.h>

// Problem constants
#define BB 16
#define SS 256
#define DD 1024
#define HH 16
#define HDD 64
#define FF 4096
#define LL 6
#define VV 32
#define MM (BB*SS)   // 4096 tokens

using bf16 = __hip_bfloat16;
using short4v = __attribute__((ext_vector_type(4))) short;
using short8 = __attribute__((ext_vector_type(8))) short;
using f32x4  = __attribute__((ext_vector_type(4))) float;

__device__ __forceinline__ float bf2f(short u){
  unsigned int x = ((unsigned int)(unsigned short)u) << 16;
  return __builtin_bit_cast(float, x);
}
__device__ __forceinline__ short f2bf(float f){
  return __builtin_bit_cast(short, __float2bfloat16(f));
}

__device__ __forceinline__ void gll16(const void* g, void* l) {
  __builtin_amdgcn_global_load_lds(
      (const __attribute__((address_space(1))) void*)g,
      (__attribute__((address_space(3))) void*)l,
      16, 0, 0);
}

__device__ __forceinline__ f32x4 mfma16(short8 a, short8 b, f32x4 c){
  return __builtin_amdgcn_mfma_f32_16x16x32_bf16(a, b, c, 0, 0, 0);
}

__device__ __forceinline__ void st_out(float* p, float v){ *p = v; }
__device__ __forceinline__ void st_out(bf16* p, float v){ *p = __float2bfloat16(v); }

// ---------------------------------------------------------------------------
// Tiled transpose + fp32->bf16 convert: in [R][C] fp32 -> out [C][R] bf16.
// ---------------------------------------------------------------------------
__global__ __launch_bounds__(256)
void tcvt64(const float* __restrict__ in, bf16* __restrict__ out,
            int R, int C, long izs, long ozs)
{
  in  += (long)blockIdx.z * izs;
  out += (long)blockIdx.z * ozs;
  __shared__ float tl[64][65];
  int c0 = blockIdx.x * 64, r0 = blockIdx.y * 64;
  int t = threadIdx.x;
  int tr = t >> 4, tc = (t & 15) * 4;
  #pragma unroll
  for (int i = 0; i < 4; ++i) {
    f32x4 v = *(const f32x4*)(in + (long)(r0 + tr + i*16) * C + c0 + tc);
    tl[tr + i*16][tc+0] = v[0];
    tl[tr + i*16][tc+1] = v[1];
    tl[tr + i*16][tc+2] = v[2];
    tl[tr + i*16][tc+3] = v[3];
  }
  __syncthreads();
  int oc = t >> 2, rch = (t & 3) * 16;
  short8 o0, o1;
  #pragma unroll
  for (int j = 0; j < 8; ++j) o0[j] = f2bf(tl[rch + j][oc]);
  #pragma unroll
  for (int j = 0; j < 8; ++j) o1[j] = f2bf(tl[rch + 8 + j][oc]);
  *(short8*)(out + (long)(c0 + oc) * R + r0 + rch)     = o0;
  *(short8*)(out + (long)(c0 + oc) * R + r0 + rch + 8) = o1;
}

// W1/W3 transpose+convert, interleaved row remap for fused SwiGLU.
// grid: (64, 16, 12): z = l*2 + (0:W1, 1:W3)
__global__ __launch_bounds__(256)
void tcvt64_w13(const float* __restrict__ W1, const float* __restrict__ W3,
                bf16* __restrict__ out)
{
  int l = blockIdx.z >> 1;
  const float* in = ((blockIdx.z & 1) ? W3 : W1) + (long)l * 1024 * 4096;
  const int zoff = (blockIdx.z & 1) ? 16 : 0;
  bf16* o = out + (long)l * 8192 * 1024;
  __shared__ float tl[64][65];
  int c0 = blockIdx.x * 64, r0 = blockIdx.y * 64;
  int t = threadIdx.x;
  int tr = t >> 4, tc = (t & 15) * 4;
  #pragma unroll
  for (int i = 0; i < 4; ++i) {
    f32x4 v = *(const f32x4*)(in + (long)(r0 + tr + i*16) * 4096 + c0 + tc);
    tl[tr + i*16][tc+0] = v[0];
    tl[tr + i*16][tc+1] = v[1];
    tl[tr + i*16][tc+2] = v[2];
    tl[tr + i*16][tc+3] = v[3];
  }
  __syncthreads();
  int oc = t >> 2, rch = (t & 3) * 16;
  short8 o0, o1;
  #pragma unroll
  for (int j = 0; j < 8; ++j) o0[j] = f2bf(tl[rch + j][oc]);
  #pragma unroll
  for (int j = 0; j < 8; ++j) o1[j] = f2bf(tl[rch + 8 + j][oc]);
  int n = c0 + oc;
  int orow = ((n >> 4) << 5) + zoff + (n & 15);
  *(short8*)(o + (long)orow * 1024 + r0 + rch)     = o0;
  *(short8*)(o + (long)orow * 1024 + r0 + rch + 8) = o1;
}

// plain fp32 -> bf16 convert; 8 elems/thread
__global__ __launch_bounds__(256)
void cvt(const float* __restrict__ in, bf16* __restrict__ out)
{
  long base = ((long)blockIdx.x * 256 + threadIdx.x) * 8;
  f32x4 a = *(const f32x4*)(in + base);
  f32x4 b = *(const f32x4*)(in + base + 4);
  short8 o;
  #pragma unroll
  for (int j = 0; j < 4; ++j) { o[j] = f2bf(a[j]); o[4+j] = f2bf(b[j]); }
  *(short8*)(out + base) = o;
}

// ---------------------------------------------------------------------------
// 256x256-tile 8-phase bf16 GEMM.
// MODE 0: plain store. MODE 1: fused SwiGLU. MODE 2: QKV with fused
//   V-transpose for branches 0/3 (V-tiles write ONLY vt, skip C).
// z decomposed 2-level: z1 = z % zdiv, z2 = z / zdiv with separate strides.
// ---------------------------------------------------------------------------
template<typename OUT, int MODE>
__global__ __launch_bounds__(512, 2)
void gemm256(const bf16* __restrict__ A, const bf16* __restrict__ Bt,
             OUT* __restrict__ C, int K,
             int lda, int ldb, int ldc,
             long az1, long bz1, long cz1, int zdiv,
             long az2, long bz2, long cz2, int swz,
             bf16* __restrict__ vtp)
{
  __shared__ short lds[65536];   // 128 KiB
  char* L = (char*)lds;
  const int z1 = blockIdx.z % zdiv, z2 = blockIdx.z / zdiv;
  A  += (long)z1 * az1 + (long)z2 * az2;
  Bt += (long)z1 * bz1 + (long)z2 * bz2;
  C  += (long)z1 * cz1 + (long)z2 * cz2;
  int lin = blockIdx.x + gridDim.x * blockIdx.y;
  if (swz) {
    int nwg = gridDim.x * gridDim.y;
    int q = nwg >> 3, r = nwg & 7;
    int xcd = lin & 7, o = lin >> 3;
    lin = (xcd < r ? xcd*(q+1) : r*(q+1) + (xcd-r)*q) + o;
  }
  const int n0 = (lin % gridDim.x) * 256;
  const int m0 = (lin / gridDim.x) * 256;
  const int t = threadIdx.x;
  const int wid = t >> 6, lane = t & 63, lo = lane & 15, hi = lane >> 4;
  const int wr = wid >> 2, wc = wid & 3;
  const int rst = t >> 3;
  const int glog = (t & 7) ^ (rst & 7);
  const int wub = wid * 1024;
  const bf16* Ap = A + (long)m0 * lda + glog * 8;
  const bf16* Bp = Bt + (long)n0 * ldb + glog * 8;
  f32x4 acc[8][4] = {};
  const int nkt = K >> 6;

  auto STAGE = [&](int kt, int p, int d) {
    const long ko = (long)kt * 64;
    char* base = L + d*65536;
    if (p < 2) {
      gll16(Ap + (long)((p*2  )*64 + rst)*lda + ko, base + (p*2  )*8192 + wub);
      gll16(Ap + (long)((p*2+1)*64 + rst)*lda + ko, base + (p*2+1)*8192 + wub);
    } else {
      int pp = p - 2;
      gll16(Bp + (long)((pp*2  )*64 + rst)*ldb + ko, base + 32768 + (pp*2  )*8192 + wub);
      gll16(Bp + (long)((pp*2+1)*64 + rst)*ldb + ko, base + 32768 + (pp*2+1)*8192 + wub);
    }
  };

  #pragma unroll
  for (int p = 0; p < 4; ++p) STAGE(0, p, 0);

  short8 af[4][2], b0[2][2], b1[2][2];
  const int gk0 = ((0*4 + hi) ^ (lo & 7)) << 4;
  const int gk1 = ((1*4 + hi) ^ (lo & 7)) << 4;

  for (int kt = 0; kt < nkt; ++kt) {
    const int d = kt & 1;
    const int ktn = (kt+1 < nkt) ? kt+1 : kt;
    char* Ab = L + d*65536;
    char* Bb = Ab + 32768;
    // ---- phase 0
    STAGE(ktn, 0, d^1);
    __builtin_amdgcn_sched_barrier(0);
    asm volatile("s_waitcnt vmcnt(2)" ::: "memory");
    __builtin_amdgcn_sched_barrier(0);
    __builtin_amdgcn_s_barrier();
    __builtin_amdgcn_sched_barrier(0);
    #pragma unroll
    for (int mi = 0; mi < 4; ++mi) {
      int r = wr*128 + mi*16 + lo;
      af[mi][0] = *(const short8*)(Ab + r*128 + gk0);
      af[mi][1] = *(const short8*)(Ab + r*128 + gk1);
    }
    #pragma unroll
    for (int ni = 0; ni < 2; ++ni) {
      int r = wc*64 + ni*16 + lo;
      b0[ni][0] = *(const short8*)(Bb + r*128 + gk0);
      b0[ni][1] = *(const short8*)(Bb + r*128 + gk1);
    }
    __builtin_amdgcn_s_barrier();
    __builtin_amdgcn_s_setprio(1);
    #pragma unroll
    for (int mi = 0; mi < 4; ++mi)
      #pragma unroll
      for (int ni = 0; ni < 2; ++ni) {
        acc[mi][ni] = mfma16(af[mi][0], b0[ni][0], acc[mi][ni]);
        acc[mi][ni] = mfma16(af[mi][1], b0[ni][1], acc[mi][ni]);
      }
    __builtin_amdgcn_s_setprio(0);
    __builtin_amdgcn_sched_barrier(0);
    __builtin_amdgcn_s_barrier();
    // ---- phase 1
    STAGE(ktn, 1, d^1);
    #pragma unroll
    for (int ni = 0; ni < 2; ++ni) {
      int r = wc*64 + (2+ni)*16 + lo;
      b1[ni][0] = *(const short8*)(Bb + r*128 + gk0);
      b1[ni][1] = *(const short8*)(Bb + r*128 + gk1);
    }
    __builtin_amdgcn_s_barrier();
    __builtin_amdgcn_s_setprio(1);
    #pragma unroll
    for (int mi = 0; mi < 4; ++mi)
      #pragma unroll
      for (int ni = 0; ni < 2; ++ni) {
        acc[mi][2+ni] = mfma16(af[mi][0], b1[ni][0], acc[mi][2+ni]);
        acc[mi][2+ni] = mfma16(af[mi][1], b1[ni][1], acc[mi][2+ni]);
      }
    __builtin_amdgcn_s_setprio(0);
    __builtin_amdgcn_sched_barrier(0);
    __builtin_amdgcn_s_barrier();
    // ---- phase 2
    STAGE(ktn, 2, d^1);
    #pragma unroll
    for (int mi = 0; mi < 4; ++mi) {
      int r = wr*128 + (4+mi)*16 + lo;
      af[mi][0] = *(const short8*)(Ab + r*128 + gk0);
      af[mi][1] = *(const short8*)(Ab + r*128 + gk1);
    }
    __builtin_amdgcn_s_barrier();
    __builtin_amdgcn_s_setprio(1);
    #pragma unroll
    for (int mi = 0; mi < 4; ++mi)
      #pragma unroll
      for (int ni = 0; ni < 2; ++ni) {
        acc[4+mi][2+ni] = mfma16(af[mi][0], b1[ni][0], acc[4+mi][2+ni]);
        acc[4+mi][2+ni] = mfma16(af[mi][1], b1[ni][1], acc[4+mi][2+ni]);
      }
    __builtin_amdgcn_s_setprio(0);
    __builtin_amdgcn_sched_barrier(0);
    __builtin_amdgcn_s_barrier();
    // ---- phase 3
    STAGE(ktn, 3, d^1);
    __builtin_amdgcn_s_barrier();
    __builtin_amdgcn_s_setprio(1);
    #pragma unroll
    for (int mi = 0; mi < 4; ++mi)
      #pragma unroll
      for (int ni = 0; ni < 2; ++ni) {
        acc[4+mi][ni] = mfma16(af[mi][0], b0[ni][0], acc[4+mi][ni]);
        acc[4+mi][ni] = mfma16(af[mi][1], b0[ni][1], acc[4+mi][ni]);
      }
    __builtin_amdgcn_s_setprio(0);
    __builtin_amdgcn_sched_barrier(0);
    __builtin_amdgcn_s_barrier();
  }
  if (MODE == 1) {
    #pragma unroll
    for (int mi = 0; mi < 8; ++mi)
      #pragma unroll
      for (int k = 0; k < 2; ++k)
        #pragma unroll
        for (int r = 0; r < 4; ++r) {
          float h1 = acc[mi][2*k][r], h3 = acc[mi][2*k+1][r];
          float sv = h1 / (1.f + __expf(-h1)) * h3;
          int row = m0 + wr*128 + mi*16 + hi*4 + r;
          int col = (n0 >> 1) + wc*32 + k*16 + lo;
          st_out(C + (long)row * ldc + col, sv);
        }
    return;
  }
  if (MODE == 2) {
    int xt = n0 / 3072, rem = n0 - xt*3072;
    if (rem >= 2048 && (xt == 0 || xt == 3)) {
      const int xc = xt ? 1 : 0;
      const int b = m0 >> 8;
      #pragma unroll
      for (int mi = 0; mi < 8; ++mi)
        #pragma unroll
        for (int ni = 0; ni < 4; ++ni) {
          int col = n0 + wc*64 + ni*16 + lo;
          int hd = col - xt*3072 - 2048;
          int h = hd >> 6, dd = hd & 63;
          int trow = wr*128 + mi*16 + hi*4;
          short4v pk;
          #pragma unroll
          for (int r = 0; r < 4; ++r) pk[r] = f2bf(acc[mi][ni][r]);
          *(short4v*)(vtp + ((long)((xc<<8)+(b<<4)+h)*64 + dd)*256 + trow) = pk;
        }
      return;
    }
  }
  #pragma unroll
  for (int mi = 0; mi < 8; ++mi)
    #pragma unroll
    for (int ni = 0; ni < 4; ++ni)
      #pragma unroll
      for (int r = 0; r < 4; ++r) {
        int row = m0 + wr*128 + mi*16 + hi*4 + r;
        int col = n0 + wc*64 + ni*16 + lo;
        st_out(C + (long)row * ldc + col, acc[mi][ni][r]);
      }
}

// ---------------------------------------------------------------------------
// Flash attention for branches {0,3}, FLAT softmax. grid: (256 bh, 2 xc).
// ---------------------------------------------------------------------------
__global__ __launch_bounds__(256)
void attn_k(const bf16* __restrict__ qkv, const bf16* __restrict__ vt,
            bf16* __restrict__ ctx)
{
  const int xc = blockIdx.y;
  const int x = xc * 3;
  const int bh = blockIdx.x;
  const int b = bh >> 4, h = bh & 15;
  const int t = threadIdx.x, wid = t >> 6, lane = t & 63;
  const int lo = lane & 15, hi = lane >> 4;
  const int q0 = wid * 64;
  const float bsc = (xc == 0) ? -0.05f : 0.0f;
  __shared__ short Pl[4][64*64];
  char* P = (char*)Pl[wid];
  const bf16* qb = qkv + (long)(b*SS) * 12288 + x*3072 + h*64;
  const bf16* kb = qb + 1024;
  const bf16* vb = vt + (long)(xc*256 + b*16 + h) * 64 * 256;

  short8 qf[4][2];
  #pragma unroll
  for (int mi = 0; mi < 4; ++mi)
    #pragma unroll
    for (int kk = 0; kk < 2; ++kk)
      qf[mi][kk] = *(const short8*)(qb + (long)(q0 + mi*16 + lo) * 12288 + kk*32 + hi*8);

  float sr[4][4];
  f32x4 aco[4][4] = {};
  #pragma unroll
  for (int i = 0; i < 4; ++i)
    #pragma unroll
    for (int r = 0; r < 4; ++r) sr[i][r] = 0.f;

  for (int c = 0; c < 4; ++c) {
    f32x4 acc[4][4] = {};
    #pragma unroll
    for (int kk = 0; kk < 2; ++kk) {
      short8 bfv[4];
      #pragma unroll
      for (int ni = 0; ni < 4; ++ni)
        bfv[ni] = *(const short8*)(kb + (long)(c*64 + ni*16 + lo) * 12288 + kk*32 + hi*8);
      #pragma unroll
      for (int mi = 0; mi < 4; ++mi)
        #pragma unroll
        for (int ni = 0; ni < 4; ++ni)
          acc[mi][ni] = mfma16(qf[mi][kk], bfv[ni], acc[mi][ni]);
    }
    // flat softmax numerator: P = exp(s/8 + bias), accumulate row sums
    #pragma unroll
    for (int mi = 0; mi < 4; ++mi)
      #pragma unroll
      for (int ni = 0; ni < 4; ++ni)
        #pragma unroll
        for (int r = 0; r < 4; ++r) {
          int lqq = mi*16 + hi*4 + r;
          int qq = q0 + lqq;
          int ttl = ni*16 + lo;
          int tt = c*64 + ttl;
          float s = fmaf(fabsf((float)(qq - tt)), bsc, acc[mi][ni][r] * 0.125f);
          float pv = __expf(s);
          sr[mi][r] += pv;
          int gph = ((ttl >> 3) ^ (lqq & 7)) << 4;
          *(bf16*)(P + lqq*128 + gph + (ttl & 7)*2) = __float2bfloat16(pv);
        }
    // PV
    #pragma unroll
    for (int kk = 0; kk < 2; ++kk) {
      short8 pf[4], vf[4];
      #pragma unroll
      for (int mi = 0; mi < 4; ++mi) {
        int qq = mi*16 + lo;
        int gph = ((kk*4 + hi) ^ (qq & 7)) << 4;
        pf[mi] = *(const short8*)(P + qq*128 + gph);
      }
      #pragma unroll
      for (int di = 0; di < 4; ++di)
        vf[di] = *(const short8*)(vb + (long)(di*16 + lo) * 256 + c*64 + kk*32 + hi*8);
      #pragma unroll
      for (int mi = 0; mi < 4; ++mi)
        #pragma unroll
        for (int di = 0; di < 4; ++di)
          aco[mi][di] = mfma16(pf[mi], vf[di], aco[mi][di]);
    }
  }
  #pragma unroll
  for (int mi = 0; mi < 4; ++mi)
    #pragma unroll
    for (int r = 0; r < 4; ++r) {
      float s = sr[mi][r];
      #pragma unroll
      for (int d = 1; d < 16; d <<= 1) s += __shfl_xor(s, d);
      sr[mi][r] = s;
    }
  bf16* cb = ctx + (long)(b*SS) * 4096 + x*1024 + h*64;
  #pragma unroll
  for (int mi = 0; mi < 4; ++mi)
    #pragma unroll
    for (int di = 0; di < 4; ++di)
      #pragma unroll
      for (int r = 0; r < 4; ++r) {
        int row = q0 + mi*16 + hi*4 + r;
        int col = di*16 + lo;
        cb[(long)row * 4096 + col] = __float2bfloat16(aco[mi][di][r] / sr[mi][r]);
      }
}

// ---------------------------------------------------------------------------
// Branches 1 (chain) and 2 (pair), flat softmax.
// grid: (B*S = 4096); wave = head-group (4 heads each) for one token.
// ---------------------------------------------------------------------------
__global__ __launch_bounds__(256)
void br12_k(const bf16* __restrict__ qkv, bf16* __restrict__ ctx)
{
  const unsigned short* Q = (const unsigned short*)qkv;
  const int wid = threadIdx.x >> 6, lane = threadIdx.x & 63;
  const int b = blockIdx.x >> 8, i = blockIdx.x & 255;
  const long rowQ = (long)(b*SS + i) * 12288;
  const long rb = (long)(b*SS) * 12288;
  const int jm = i > 0 ? i-1 : 0;
  const int jp = i < SS-1 ? i+1 : SS-1;
  const int j0 = i & ~1, j1 = j0 | 1;
  unsigned short* outp = (unsigned short*)ctx + (long)(b*SS + i) * 4096;
  #pragma unroll
  for (int hh = 0; hh < 4; ++hh) {
    const int h = wid*4 + hh;
    const int off1 = 3072 + h*64 + lane;
    const int off2 = 6144 + h*64 + lane;
    float q1d = bf2f(Q[rowQ + off1]);
    float q2d = bf2f(Q[rowQ + off2]);
    float km = bf2f(Q[rb + (long)jm*12288 + off1 + 1024]);
    float k0 = bf2f(Q[rb + (long)i *12288 + off1 + 1024]);
    float kp = bf2f(Q[rb + (long)jp*12288 + off1 + 1024]);
    float ka = bf2f(Q[rb + (long)j0*12288 + off2 + 1024]);
    float kb_ = bf2f(Q[rb + (long)j1*12288 + off2 + 1024]);
    float s0 = q1d*km, s1 = q1d*k0, s2 = q1d*kp, s3 = q2d*ka, s4 = q2d*kb_;
    #pragma unroll
    for (int st = 1; st < 64; st <<= 1) {
      s0 += __shfl_xor(s0, st); s1 += __shfl_xor(s1, st); s2 += __shfl_xor(s2, st);
      s3 += __shfl_xor(s3, st); s4 += __shfl_xor(s4, st);
    }
    float lm = s0*0.125f + (i > 0      ? 0.f : -1e30f);
    float l0 = s1*0.125f;
    float lp = s2*0.125f + (i < SS-1   ? 0.f : -1e30f);
    float pm = __expf(lm), p0 = __expf(l0), pp = __expf(lp);
    float vm = bf2f(Q[rb + (long)jm*12288 + off1 + 2048]);
    float v0 = bf2f(Q[rb + (long)i *12288 + off1 + 2048]);
    float vp = bf2f(Q[rb + (long)jp*12288 + off1 + 2048]);
    float o1 = (pm*vm + p0*v0 + pp*vp) / (pm+p0+pp);
    float la = s3*0.125f, lb = s4*0.125f;
    float pa = __expf(la), pb = __expf(lb);
    float va = bf2f(Q[rb + (long)j0*12288 + off2 + 2048]);
    float vb2= bf2f(Q[rb + (long)j1*12288 + off2 + 2048]);
    float o2 = (pa*va + pb*vb2) / (pa+pb);
    outp[1024 + h*64 + lane] = (unsigned short)f2bf(o1);
    outp[2048 + h*64 + lane] = (unsigned short)f2bf(o2);
  }
}

// ---------------------------------------------------------------------------
// Fused residual + LayerNorm + adaLN modulation.
// XBF=0: xin fp32; XBF=1: xin bf16. xout (residual stream) stored bf16.
// ---------------------------------------------------------------------------
template<int XBF>
__global__ __launch_bounds__(256)
void ln_fused(const void* __restrict__ xin, const bf16* __restrict__ y,
              int ycnt, long ystride,
              const float* __restrict__ ybias, const float* __restrict__ gate,
              const float* __restrict__ lnw, const float* __restrict__ lnb,
              const float* __restrict__ sc, const float* __restrict__ sh,
              bf16* __restrict__ xout, bf16* __restrict__ xnbf,
              float* __restrict__ xnf)
{
  int row = blockIdx.x;
  int b = row >> 8;
  int t = threadIdx.x;
  int d0 = t * 4;
  float v[4];
  if (XBF) {
    short4v xv = *(const short4v*)((const bf16*)xin + (long)row * DD + d0);
    #pragma unroll
    for (int j = 0; j < 4; ++j) v[j] = bf2f(xv[j]);
  } else {
    f32x4 xi = *(const f32x4*)((const float*)xin + (long)row * DD + d0);
    #pragma unroll
    for (int j = 0; j < 4; ++j) v[j] = xi[j];
  }
  if (y) {
    f32x4 ys = {};
    for (int jp = 0; jp < ycnt; ++jp) {
      short4v yv = *(const short4v*)(y + jp*ystride + (long)row * DD + d0);
      #pragma unroll
      for (int j = 0; j < 4; ++j) ys[j] += bf2f(yv[j]);
    }
    #pragma unroll
    for (int j = 0; j < 4; ++j) {
      float yy = ys[j] + (ybias ? ybias[d0+j] : 0.f);
      v[j] += gate[b*6144 + d0 + j] * yy;
    }
  }
  if (xout) {
    short4v o;
    #pragma unroll
    for (int j = 0; j < 4; ++j) o[j] = f2bf(v[j]);
    *(short4v*)(xout + (long)row * DD + d0) = o;
  }
  float s = v[0]+v[1]+v[2]+v[3];
  float s2 = v[0]*v[0]+v[1]*v[1]+v[2]*v[2]+v[3]*v[3];
  #pragma unroll
  for (int d = 1; d < 64; d <<= 1) { s += __shfl_xor(s, d); s2 += __shfl_xor(s2, d); }
  __shared__ float rs[4][2];
  int wid = t >> 6, lane = t & 63;
  if (lane == 0) { rs[wid][0] = s; rs[wid][1] = s2; }
  __syncthreads();
  s  = rs[0][0]+rs[1][0]+rs[2][0]+rs[3][0];
  s2 = rs[0][1]+rs[1][1]+rs[2][1]+rs[3][1];
  float mean = s * (1.f/1024.f);
  float var  = s2 * (1.f/1024.f) - mean*mean;
  float rstd = rsqrtf(var + 1e-6f);
  #pragma unroll
  for (int j = 0; j < 4; ++j) {
    int d = d0 + j;
    float xn = (v[j] - mean) * rstd * lnw[d] + lnb[d];
    if (sc) {
      float val = xn * (1.f + sc[b*6144 + d]) + sh[b*6144 + d];
      xnbf[(long)row * DD + d] = __float2bfloat16(val);
    } else if (xnbf) {
      xnbf[(long)row * DD + d] = __float2bfloat16(xn);
    } else {
      xnf[(long)row * DD + d] = xn;
    }
  }
}

// ---------------------------------------------------------------------------
// adaLN: fused silu(t_emb) + split-K partial GEMM, then reduce.
// ---------------------------------------------------------------------------
__global__ __launch_bounds__(256)
void a_gemm(const float* __restrict__ Wa, const float* __restrict__ te,
            float* __restrict__ partial)
{
  int l = blockIdx.z, kc = blockIdx.y;
  int n0 = (blockIdx.x * 256 + threadIdx.x) * 4;
  __shared__ float sl[16*128];
  for (int i = threadIdx.x; i < 16*128; i += 256) {
    int m = i >> 7, k = i & 127;
    float v = te[m*1024 + kc*128 + k];
    sl[i] = v / (1.f + __expf(-v));        // fused SiLU
  }
  __syncthreads();
  f32x4 acc[16] = {};
  const float* wp = Wa + (long)l * DD * 6144 + (long)(kc*128) * 6144 + n0;
  #pragma unroll 4
  for (int k = 0; k < 128; ++k) {
    f32x4 w = *(const f32x4*)(wp + (long)k * 6144);
    #pragma unroll
    for (int m = 0; m < 16; ++m) {
      float sv = sl[m*128 + k];
      #pragma unroll
      for (int j = 0; j < 4; ++j) acc[m][j] += sv * w[j];
    }
  }
  #pragma unroll
  for (int m = 0; m < 16; ++m)
    *(f32x4*)(partial + ((long)(l*8 + kc)*16 + m) * 6144 + n0) = acc[m];
}

__global__ __launch_bounds__(256)
void a_red(const float* __restrict__ partial, const float* __restrict__ ba,
           float* __restrict__ a_all)
{
  int idx = blockIdx.x * 256 + threadIdx.x;
  int n = idx % 6144;
  int lm = idx / 6144;
  int l = lm >> 4, m = lm & 15;
  float s = 0.f;
  #pragma unroll
  for (int kc = 0; kc < 8; ++kc)
    s += partial[((long)(l*8 + kc)*16 + m) * 6144 + n];
  a_all[(long)(l*16 + m) * 6144 + n] = s + ba[(long)l * 6144 + n];
}

// ---------------------------------------------------------------------------
// Final projection
// ---------------------------------------------------------------------------
__global__ __launch_bounds__(256)
void proj_k(const float* __restrict__ xnf, const float* __restrict__ Wp,
            const float* __restrict__ bp, float* __restrict__ out)
{
  int v = threadIdx.x & 31, tg = threadIdx.x >> 5;
  int s = blockIdx.x * 8 + tg;
  const float* xr = xnf + (long)s * DD;
  float acc = bp[v];
  #pragma unroll 8
  for (int k = 0; k < DD; ++k) acc += xr[k] * Wp[(long)k * VV + v];
  out[(long)s * VV + v] = acc;
}

// ---------------------------------------------------------------------------
extern "C" void kernel_launch(void* const* d_in, const int* in_sizes, int n_in,
                              void* d_out, int out_size, void* d_ws, size_t ws_size,
                              hipStream_t stream)
{
  (void)in_sizes; (void)n_in; (void)out_size; (void)ws_size;
  const float* x_in = (const float*)d_in[0];
  const float* t_emb= (const float*)d_in[1];
  const float* ln1w = (const float*)d_in[2];
  const float* ln1b = (const float*)d_in[3];
  const float* ln2w = (const float*)d_in[4];
  const float* ln2b = (const float*)d_in[5];
  const float* Wqkv = (const float*)d_in[6];
  const float* Wo   = (const float*)d_in[7];
  const float* Wf   = (const float*)d_in[8];
  const float* bfb  = (const float*)d_in[9];
  const float* W1   = (const float*)d_in[10];
  const float* W3   = (const float*)d_in[11];
  const float* W2   = (const float*)d_in[12];
  const float* Wa   = (const float*)d_in[13];
  const float* ba   = (const float*)d_in[14];
  const float* fnw  = (const float*)d_in[15];
  const float* fnb  = (const float*)d_in[16];
  const float* Wp   = (const float*)d_in[17];
  const float* bp   = (const float*)d_in[18];
  float* out = (float*)d_out;

  char* p = (char*)d_ws;
  auto alloc = [&](size_t bytes) { char* r = p; p += (bytes + 255) & ~(size_t)255; return r; };
  bf16* wqkv_t = (bf16*)alloc(6L*4*3072*1024*2);
  bf16* wo_b   = (bf16*)alloc(6L*4*1024*1024*2);
  bf16* wf_t   = (bf16*)alloc(6L*1024*4096*2);
  bf16* wof_t  = (bf16*)alloc(6L*1024*4096*2);
  bf16* w13i_t = (bf16*)alloc(6L*8192*1024*2);
  bf16* w2_t   = (bf16*)alloc(6L*1024*4096*2);
  float* a_all = (float*)alloc(6L*16*6144*4);
  float* a_par = (float*)alloc(6L*8*16*6144*4);
  bf16* x_buf  = (bf16*)alloc((long)MM*DD*2);      // bf16 residual stream
  bf16* xn     = (bf16*)alloc((long)MM*DD*2);
  char* bufA   = alloc((long)MM*12288*2);          // qkv
  bf16* vt     = (bf16*)alloc(2L*16*16*64*256*2);
  bf16* ctx    = (bf16*)alloc((long)MM*4096*2);    // K-concat layout
  char* bufB   = alloc((long)MM*4096*2);           // hg | xnf(fp32)
  bf16* gy     = (bf16*)alloc(4L*MM*DD*2);         // 4 bf16 split-K partials

  bf16* qkvb = (bf16*)bufA;
  bf16* hg   = (bf16*)bufB;
  float* xnf = (float*)bufB;
  const long MMDD = (long)MM*DD;

  // --- upfront: adaLN + ALL weight conversions (batched across layers) ---
  a_gemm<<<dim3(6, 8, 6), 256, 0, stream>>>(Wa, t_emb, a_par);
  a_red<<<dim3(2304), 256, 0, stream>>>(a_par, ba, a_all);
  tcvt64<<<dim3(48,16,24),256,0,stream>>>(Wqkv, wqkv_t, 1024, 3072, 1024L*3072, 3072L*1024);
  cvt<<<dim3(12288),256,0,stream>>>(Wo, wo_b);
  tcvt64<<<dim3(16,64,6),256,0,stream>>>(Wf, wf_t, 4096, 1024, 4096L*1024, 4096L*1024);
  tcvt64_w13<<<dim3(64,16,12),256,0,stream>>>(W1, W3, w13i_t);
  tcvt64<<<dim3(16,64,6),256,0,stream>>>(W2, w2_t, 4096, 1024, 4096L*1024, 4096L*1024);
  // Wof[l][x]: z = l*4 + x
  gemm256<bf16,0><<<dim3(4,4,24),512,0,stream>>>(wf_t, wo_b, wof_t,
      1024, 4096, 1024, 4096,
      1024L, 1024L*1024, 1024L, 4,
      1024L*4096, 4L*1024*1024, 1024L*4096, 0, nullptr);

  const long aL = 16L * 6144;
  ln_fused<0><<<4096,256,0,stream>>>(x_in, nullptr, 0, 0, nullptr, nullptr,
                                     ln1w, ln1b, a_all+1024, a_all+0,
                                     nullptr, xn, nullptr);

  for (int l = 0; l < LL; ++l) {
    const float* a_l = a_all + (long)l * aL;
    // QKV with fused V-transpose for branches 0/3
    gemm256<bf16,2><<<dim3(48,16,1),512,0,stream>>>(xn, wqkv_t + (long)l*4*3072*1024,
        qkvb, 1024, 1024, 1024, 12288, 0,0,0, 1, 0,0,0, 1, vt);
    attn_k<<<dim3(256,2),256,0,stream>>>(qkvb, vt, ctx);
    br12_k<<<dim3(4096),256,0,stream>>>(qkvb, ctx);
    // gy[z] = ctx @ Wof (split-K=4, bf16 partials)
    gemm256<bf16,0><<<dim3(4,16,4),512,0,stream>>>(ctx, wof_t + (long)l*1024*4096,
        gy, 1024, 4096, 4096, 1024, 1024L, 1024L, MMDD, 4, 0,0,0, 1, nullptr);
    if (l == 0)
      ln_fused<0><<<4096,256,0,stream>>>(x_in, gy, 4, MMDD,
                                         bfb, a_l+2048,
                                         ln2w, ln2b,
                                         a_l+4096, a_l+3072, x_buf, xn, nullptr);
    else
      ln_fused<1><<<4096,256,0,stream>>>(x_buf, gy, 4, MMDD,
                                         bfb + (long)l*1024, a_l+2048,
                                         ln2w + (long)l*1024, ln2b + (long)l*1024,
                                         a_l+4096, a_l+3072, x_buf, xn, nullptr);
    // hg = swiglu(xn @ W13) fused
    gemm256<bf16,1><<<dim3(32,16,1),512,0,stream>>>(xn, w13i_t + (long)l*8192*1024,
        hg, 1024, 1024, 1024, 4096, 0,0,0, 1, 0,0,0, 1, nullptr);
    // gy[z] = hg @ W2 (split-K=4, bf16 partials)
    gemm256<bf16,0><<<dim3(4,16,4),512,0,stream>>>(hg, w2_t + (long)l*1024*4096,
        gy, 1024, 4096, 4096, 1024, 1024L, 1024L, MMDD, 4, 0,0,0, 1, nullptr);
    if (l < LL-1)
      ln_fused<1><<<4096,256,0,stream>>>(x_buf, gy, 4, MMDD, nullptr, a_l+5120,
                                         ln1w + (long)(l+1)*1024, ln1b + (long)(l+1)*1024,
                                         a_all + (long)(l+1)*aL + 1024, a_all + (long)(l+1)*aL,
                                         x_buf, xn, nullptr);
    else
      ln_fused<1><<<4096,256,0,stream>>>(x_buf, gy, 4, MMDD, nullptr, a_l+5120,
                                         fnw, fnb, nullptr, nullptr,
                                         x_buf, nullptr, xnf);
  }
  proj_k<<<dim3(512),256,0,stream>>>(xnf, Wp, bp, out);
}

// Round 14
// 2748.065 us; speedup vs baseline: 1.0632x; 1.0016x over previous
//
#include <hip/hip_runtime.h>
#include <hip/hip_bf16.h>
#include <math.h>

// Problem constants
#define BB 16
#define SS 256
#define DD 1024
#define HH 16
#define HDD 64
#define FF 4096
#define LL 6
#define VV 32
#define MM (BB*SS)   // 4096 tokens

using bf16 = __hip_bfloat16;
using short4v = __attribute__((ext_vector_type(4))) short;
using short8 = __attribute__((ext_vector_type(8))) short;
using f32x4  = __attribute__((ext_vector_type(4))) float;

// packed Q/K region offset within the vt buffer (elements)
#define QKOFF (2L*256*64*256)

__device__ __forceinline__ float bf2f(short u){
  unsigned int x = ((unsigned int)(unsigned short)u) << 16;
  return __builtin_bit_cast(float, x);
}
__device__ __forceinline__ short f2bf(float f){
  return __builtin_bit_cast(short, __float2bfloat16(f));
}

__device__ __forceinline__ void gll16(const void* g, void* l) {
  __builtin_amdgcn_global_load_lds(
      (const __attribute__((address_space(1))) void*)g,
      (__attribute__((address_space(3))) void*)l,
      16, 0, 0);
}

__device__ __forceinline__ f32x4 mfma16(short8 a, short8 b, f32x4 c){
  return __builtin_amdgcn_mfma_f32_16x16x32_bf16(a, b, c, 0, 0, 0);
}

__device__ __forceinline__ void st_out(float* p, float v){ *p = v; }
__device__ __forceinline__ void st_out(bf16* p, float v){ *p = __float2bfloat16(v); }

// ---------------------------------------------------------------------------
// Tiled transpose + fp32->bf16 convert: in [R][C] fp32 -> out [C][R] bf16.
// ---------------------------------------------------------------------------
__global__ __launch_bounds__(256)
void tcvt64(const float* __restrict__ in, bf16* __restrict__ out,
            int R, int C, long izs, long ozs)
{
  in  += (long)blockIdx.z * izs;
  out += (long)blockIdx.z * ozs;
  __shared__ float tl[64][65];
  int c0 = blockIdx.x * 64, r0 = blockIdx.y * 64;
  int t = threadIdx.x;
  int tr = t >> 4, tc = (t & 15) * 4;
  #pragma unroll
  for (int i = 0; i < 4; ++i) {
    f32x4 v = *(const f32x4*)(in + (long)(r0 + tr + i*16) * C + c0 + tc);
    tl[tr + i*16][tc+0] = v[0];
    tl[tr + i*16][tc+1] = v[1];
    tl[tr + i*16][tc+2] = v[2];
    tl[tr + i*16][tc+3] = v[3];
  }
  __syncthreads();
  int oc = t >> 2, rch = (t & 3) * 16;
  short8 o0, o1;
  #pragma unroll
  for (int j = 0; j < 8; ++j) o0[j] = f2bf(tl[rch + j][oc]);
  #pragma unroll
  for (int j = 0; j < 8; ++j) o1[j] = f2bf(tl[rch + 8 + j][oc]);
  *(short8*)(out + (long)(c0 + oc) * R + r0 + rch)     = o0;
  *(short8*)(out + (long)(c0 + oc) * R + r0 + rch + 8) = o1;
}

// W1/W3 transpose+convert, interleaved row remap for fused SwiGLU.
// grid: (64, 16, 12): z = l*2 + (0:W1, 1:W3)
__global__ __launch_bounds__(256)
void tcvt64_w13(const float* __restrict__ W1, const float* __restrict__ W3,
                bf16* __restrict__ out)
{
  int l = blockIdx.z >> 1;
  const float* in = ((blockIdx.z & 1) ? W3 : W1) + (long)l * 1024 * 4096;
  const int zoff = (blockIdx.z & 1) ? 16 : 0;
  bf16* o = out + (long)l * 8192 * 1024;
  __shared__ float tl[64][65];
  int c0 = blockIdx.x * 64, r0 = blockIdx.y * 64;
  int t = threadIdx.x;
  int tr = t >> 4, tc = (t & 15) * 4;
  #pragma unroll
  for (int i = 0; i < 4; ++i) {
    f32x4 v = *(const f32x4*)(in + (long)(r0 + tr + i*16) * 4096 + c0 + tc);
    tl[tr + i*16][tc+0] = v[0];
    tl[tr + i*16][tc+1] = v[1];
    tl[tr + i*16][tc+2] = v[2];
    tl[tr + i*16][tc+3] = v[3];
  }
  __syncthreads();
  int oc = t >> 2, rch = (t & 3) * 16;
  short8 o0, o1;
  #pragma unroll
  for (int j = 0; j < 8; ++j) o0[j] = f2bf(tl[rch + j][oc]);
  #pragma unroll
  for (int j = 0; j < 8; ++j) o1[j] = f2bf(tl[rch + 8 + j][oc]);
  int n = c0 + oc;
  int orow = ((n >> 4) << 5) + zoff + (n & 15);
  *(short8*)(o + (long)orow * 1024 + r0 + rch)     = o0;
  *(short8*)(o + (long)orow * 1024 + r0 + rch + 8) = o1;
}

// plain fp32 -> bf16 convert; 8 elems/thread
__global__ __launch_bounds__(256)
void cvt(const float* __restrict__ in, bf16* __restrict__ out)
{
  long base = ((long)blockIdx.x * 256 + threadIdx.x) * 8;
  f32x4 a = *(const f32x4*)(in + base);
  f32x4 b = *(const f32x4*)(in + base + 4);
  short8 o;
  #pragma unroll
  for (int j = 0; j < 4; ++j) { o[j] = f2bf(a[j]); o[4+j] = f2bf(b[j]); }
  *(short8*)(out + base) = o;
}

// ---------------------------------------------------------------------------
// 256x256-tile 8-phase bf16 GEMM.
// MODE 0: plain store. MODE 1: fused SwiGLU. MODE 2: QKV; branch-0/3 tiles
//   redirect: V -> transposed vt, Q/K -> packed per-head [t][64] buffers
//   (qkvb store skipped for those tiles).
// z decomposed 2-level: z1 = z % zdiv, z2 = z / zdiv with separate strides.
// ---------------------------------------------------------------------------
template<typename OUT, int MODE>
__global__ __launch_bounds__(512, 2)
void gemm256(const bf16* __restrict__ A, const bf16* __restrict__ Bt,
             OUT* __restrict__ C, int K,
             int lda, int ldb, int ldc,
             long az1, long bz1, long cz1, int zdiv,
             long az2, long bz2, long cz2, int swz,
             bf16* __restrict__ vtp)
{
  __shared__ short lds[65536];   // 128 KiB
  char* L = (char*)lds;
  const int z1 = blockIdx.z % zdiv, z2 = blockIdx.z / zdiv;
  A  += (long)z1 * az1 + (long)z2 * az2;
  Bt += (long)z1 * bz1 + (long)z2 * bz2;
  C  += (long)z1 * cz1 + (long)z2 * cz2;
  int lin = blockIdx.x + gridDim.x * blockIdx.y;
  if (swz) {
    int nwg = gridDim.x * gridDim.y;
    int q = nwg >> 3, r = nwg & 7;
    int xcd = lin & 7, o = lin >> 3;
    lin = (xcd < r ? xcd*(q+1) : r*(q+1) + (xcd-r)*q) + o;
  }
  const int n0 = (lin % gridDim.x) * 256;
  const int m0 = (lin / gridDim.x) * 256;
  const int t = threadIdx.x;
  const int wid = t >> 6, lane = t & 63, lo = lane & 15, hi = lane >> 4;
  const int wr = wid >> 2, wc = wid & 3;
  const int rst = t >> 3;
  const int glog = (t & 7) ^ (rst & 7);
  const int wub = wid * 1024;
  const bf16* Ap = A + (long)m0 * lda + glog * 8;
  const bf16* Bp = Bt + (long)n0 * ldb + glog * 8;
  f32x4 acc[8][4] = {};
  const int nkt = K >> 6;

  auto STAGE = [&](int kt, int p, int d) {
    const long ko = (long)kt * 64;
    char* base = L + d*65536;
    if (p < 2) {
      gll16(Ap + (long)((p*2  )*64 + rst)*lda + ko, base + (p*2  )*8192 + wub);
      gll16(Ap + (long)((p*2+1)*64 + rst)*lda + ko, base + (p*2+1)*8192 + wub);
    } else {
      int pp = p - 2;
      gll16(Bp + (long)((pp*2  )*64 + rst)*ldb + ko, base + 32768 + (pp*2  )*8192 + wub);
      gll16(Bp + (long)((pp*2+1)*64 + rst)*ldb + ko, base + 32768 + (pp*2+1)*8192 + wub);
    }
  };

  #pragma unroll
  for (int p = 0; p < 4; ++p) STAGE(0, p, 0);

  short8 af[4][2], b0[2][2], b1[2][2];
  const int gk0 = ((0*4 + hi) ^ (lo & 7)) << 4;
  const int gk1 = ((1*4 + hi) ^ (lo & 7)) << 4;

  for (int kt = 0; kt < nkt; ++kt) {
    const int d = kt & 1;
    const int ktn = (kt+1 < nkt) ? kt+1 : kt;
    char* Ab = L + d*65536;
    char* Bb = Ab + 32768;
    // ---- phase 0
    STAGE(ktn, 0, d^1);
    __builtin_amdgcn_sched_barrier(0);
    asm volatile("s_waitcnt vmcnt(2)" ::: "memory");
    __builtin_amdgcn_sched_barrier(0);
    __builtin_amdgcn_s_barrier();
    __builtin_amdgcn_sched_barrier(0);
    #pragma unroll
    for (int mi = 0; mi < 4; ++mi) {
      int r = wr*128 + mi*16 + lo;
      af[mi][0] = *(const short8*)(Ab + r*128 + gk0);
      af[mi][1] = *(const short8*)(Ab + r*128 + gk1);
    }
    #pragma unroll
    for (int ni = 0; ni < 2; ++ni) {
      int r = wc*64 + ni*16 + lo;
      b0[ni][0] = *(const short8*)(Bb + r*128 + gk0);
      b0[ni][1] = *(const short8*)(Bb + r*128 + gk1);
    }
    __builtin_amdgcn_s_barrier();
    __builtin_amdgcn_s_setprio(1);
    #pragma unroll
    for (int mi = 0; mi < 4; ++mi)
      #pragma unroll
      for (int ni = 0; ni < 2; ++ni) {
        acc[mi][ni] = mfma16(af[mi][0], b0[ni][0], acc[mi][ni]);
        acc[mi][ni] = mfma16(af[mi][1], b0[ni][1], acc[mi][ni]);
      }
    __builtin_amdgcn_s_setprio(0);
    __builtin_amdgcn_sched_barrier(0);
    __builtin_amdgcn_s_barrier();
    // ---- phase 1
    STAGE(ktn, 1, d^1);
    #pragma unroll
    for (int ni = 0; ni < 2; ++ni) {
      int r = wc*64 + (2+ni)*16 + lo;
      b1[ni][0] = *(const short8*)(Bb + r*128 + gk0);
      b1[ni][1] = *(const short8*)(Bb + r*128 + gk1);
    }
    __builtin_amdgcn_s_barrier();
    __builtin_amdgcn_s_setprio(1);
    #pragma unroll
    for (int mi = 0; mi < 4; ++mi)
      #pragma unroll
      for (int ni = 0; ni < 2; ++ni) {
        acc[mi][2+ni] = mfma16(af[mi][0], b1[ni][0], acc[mi][2+ni]);
        acc[mi][2+ni] = mfma16(af[mi][1], b1[ni][1], acc[mi][2+ni]);
      }
    __builtin_amdgcn_s_setprio(0);
    __builtin_amdgcn_sched_barrier(0);
    __builtin_amdgcn_s_barrier();
    // ---- phase 2
    STAGE(ktn, 2, d^1);
    #pragma unroll
    for (int mi = 0; mi < 4; ++mi) {
      int r = wr*128 + (4+mi)*16 + lo;
      af[mi][0] = *(const short8*)(Ab + r*128 + gk0);
      af[mi][1] = *(const short8*)(Ab + r*128 + gk1);
    }
    __builtin_amdgcn_s_barrier();
    __builtin_amdgcn_s_setprio(1);
    #pragma unroll
    for (int mi = 0; mi < 4; ++mi)
      #pragma unroll
      for (int ni = 0; ni < 2; ++ni) {
        acc[4+mi][2+ni] = mfma16(af[mi][0], b1[ni][0], acc[4+mi][2+ni]);
        acc[4+mi][2+ni] = mfma16(af[mi][1], b1[ni][1], acc[4+mi][2+ni]);
      }
    __builtin_amdgcn_s_setprio(0);
    __builtin_amdgcn_sched_barrier(0);
    __builtin_amdgcn_s_barrier();
    // ---- phase 3
    STAGE(ktn, 3, d^1);
    __builtin_amdgcn_s_barrier();
    __builtin_amdgcn_s_setprio(1);
    #pragma unroll
    for (int mi = 0; mi < 4; ++mi)
      #pragma unroll
      for (int ni = 0; ni < 2; ++ni) {
        acc[4+mi][ni] = mfma16(af[mi][0], b0[ni][0], acc[4+mi][ni]);
        acc[4+mi][ni] = mfma16(af[mi][1], b0[ni][1], acc[4+mi][ni]);
      }
    __builtin_amdgcn_s_setprio(0);
    __builtin_amdgcn_sched_barrier(0);
    __builtin_amdgcn_s_barrier();
  }
  if (MODE == 1) {
    #pragma unroll
    for (int mi = 0; mi < 8; ++mi)
      #pragma unroll
      for (int k = 0; k < 2; ++k)
        #pragma unroll
        for (int r = 0; r < 4; ++r) {
          float h1 = acc[mi][2*k][r], h3 = acc[mi][2*k+1][r];
          float sv = h1 / (1.f + __expf(-h1)) * h3;
          int row = m0 + wr*128 + mi*16 + hi*4 + r;
          int col = (n0 >> 1) + wc*32 + k*16 + lo;
          st_out(C + (long)row * ldc + col, sv);
        }
    return;
  }
  if (MODE == 2) {
    int xt = n0 / 3072, rem = n0 - xt*3072;
    if (xt == 0 || xt == 3) {
      const int xc = xt ? 1 : 0;
      const int b = m0 >> 8;
      if (rem >= 2048) {
        // V tile: write transposed vt only
        #pragma unroll
        for (int mi = 0; mi < 8; ++mi)
          #pragma unroll
          for (int ni = 0; ni < 4; ++ni) {
            int col = n0 + wc*64 + ni*16 + lo;
            int hd = col - xt*3072 - 2048;
            int h = hd >> 6, dd = hd & 63;
            int trow = wr*128 + mi*16 + hi*4;
            short4v pk;
            #pragma unroll
            for (int r = 0; r < 4; ++r) pk[r] = f2bf(acc[mi][ni][r]);
            *(short4v*)(vtp + ((long)((xc<<8)+(b<<4)+h)*64 + dd)*256 + trow) = pk;
          }
      } else {
        // Q or K tile: packed per-head row-major [xc][sec][bh][t][64]
        const int sec = rem >> 10;     // 0=Q, 1=K
        bf16* qkp = vtp + QKOFF;
        #pragma unroll
        for (int mi = 0; mi < 8; ++mi)
          #pragma unroll
          for (int ni = 0; ni < 4; ++ni) {
            int colb = rem - sec*1024 + wc*64 + ni*16 + lo;   // 0..1023
            int h = colb >> 6, dd = colb & 63;
            int trow = wr*128 + mi*16 + hi*4;
            bf16* dst = qkp + (((long)((xc*2+sec)*256 + (b<<4) + h)) << 14)
                        + (long)trow*64 + dd;
            #pragma unroll
            for (int r = 0; r < 4; ++r)
              dst[r*64] = __float2bfloat16(acc[mi][ni][r]);
          }
      }
      return;
    }
  }
  #pragma unroll
  for (int mi = 0; mi < 8; ++mi)
    #pragma unroll
    for (int ni = 0; ni < 4; ++ni)
      #pragma unroll
      for (int r = 0; r < 4; ++r) {
        int row = m0 + wr*128 + mi*16 + hi*4 + r;
        int col = n0 + wc*64 + ni*16 + lo;
        st_out(C + (long)row * ldc + col, acc[mi][ni][r]);
      }
}

// ---------------------------------------------------------------------------
// Flash attention for branches {0,3}, FLAT softmax, packed Q/K/V inputs.
// grid: (256 bh, 2 xc).
// ---------------------------------------------------------------------------
__global__ __launch_bounds__(256)
void attn_k(const bf16* __restrict__ vtp, bf16* __restrict__ ctx)
{
  const int xc = blockIdx.y;
  const int x = xc * 3;
  const int bh = blockIdx.x;
  const int b = bh >> 4, h = bh & 15;
  const int t = threadIdx.x, wid = t >> 6, lane = t & 63;
  const int lo = lane & 15, hi = lane >> 4;
  const int q0 = wid * 64;
  const float bsc = (xc == 0) ? -0.05f : 0.0f;
  __shared__ short Pl[4][64*64];
  char* P = (char*)Pl[wid];
  const bf16* qkp = vtp + QKOFF;
  const bf16* qb = qkp + (((long)((xc*2+0)*256 + (b<<4) + h)) << 14);
  const bf16* kb = qkp + (((long)((xc*2+1)*256 + (b<<4) + h)) << 14);
  const bf16* vb = vtp + (long)(xc*256 + b*16 + h) * 64 * 256;

  short8 qf[4][2];
  #pragma unroll
  for (int mi = 0; mi < 4; ++mi)
    #pragma unroll
    for (int kk = 0; kk < 2; ++kk)
      qf[mi][kk] = *(const short8*)(qb + (long)(q0 + mi*16 + lo) * 64 + kk*32 + hi*8);

  float sr[4][4];
  f32x4 aco[4][4] = {};
  #pragma unroll
  for (int i = 0; i < 4; ++i)
    #pragma unroll
    for (int r = 0; r < 4; ++r) sr[i][r] = 0.f;

  for (int c = 0; c < 4; ++c) {
    f32x4 acc[4][4] = {};
    #pragma unroll
    for (int kk = 0; kk < 2; ++kk) {
      short8 bfv[4];
      #pragma unroll
      for (int ni = 0; ni < 4; ++ni)
        bfv[ni] = *(const short8*)(kb + (long)(c*64 + ni*16 + lo) * 64 + kk*32 + hi*8);
      #pragma unroll
      for (int mi = 0; mi < 4; ++mi)
        #pragma unroll
        for (int ni = 0; ni < 4; ++ni)
          acc[mi][ni] = mfma16(qf[mi][kk], bfv[ni], acc[mi][ni]);
    }
    // flat softmax numerator: P = exp(s/8 + bias), accumulate row sums
    #pragma unroll
    for (int mi = 0; mi < 4; ++mi)
      #pragma unroll
      for (int ni = 0; ni < 4; ++ni)
        #pragma unroll
        for (int r = 0; r < 4; ++r) {
          int lqq = mi*16 + hi*4 + r;
          int qq = q0 + lqq;
          int ttl = ni*16 + lo;
          int tt = c*64 + ttl;
          float s = fmaf(fabsf((float)(qq - tt)), bsc, acc[mi][ni][r] * 0.125f);
          float pv = __expf(s);
          sr[mi][r] += pv;
          int gph = ((ttl >> 3) ^ (lqq & 7)) << 4;
          *(bf16*)(P + lqq*128 + gph + (ttl & 7)*2) = __float2bfloat16(pv);
        }
    // PV
    #pragma unroll
    for (int kk = 0; kk < 2; ++kk) {
      short8 pf[4], vf[4];
      #pragma unroll
      for (int mi = 0; mi < 4; ++mi) {
        int qq = mi*16 + lo;
        int gph = ((kk*4 + hi) ^ (qq & 7)) << 4;
        pf[mi] = *(const short8*)(P + qq*128 + gph);
      }
      #pragma unroll
      for (int di = 0; di < 4; ++di)
        vf[di] = *(const short8*)(vb + (long)(di*16 + lo) * 256 + c*64 + kk*32 + hi*8);
      #pragma unroll
      for (int mi = 0; mi < 4; ++mi)
        #pragma unroll
        for (int di = 0; di < 4; ++di)
          aco[mi][di] = mfma16(pf[mi], vf[di], aco[mi][di]);
    }
  }
  #pragma unroll
  for (int mi = 0; mi < 4; ++mi)
    #pragma unroll
    for (int r = 0; r < 4; ++r) {
      float s = sr[mi][r];
      #pragma unroll
      for (int d = 1; d < 16; d <<= 1) s += __shfl_xor(s, d);
      sr[mi][r] = s;
    }
  bf16* cb = ctx + (long)(b*SS) * 4096 + x*1024 + h*64;
  #pragma unroll
  for (int mi = 0; mi < 4; ++mi)
    #pragma unroll
    for (int di = 0; di < 4; ++di)
      #pragma unroll
      for (int r = 0; r < 4; ++r) {
        int row = q0 + mi*16 + hi*4 + r;
        int col = di*16 + lo;
        cb[(long)row * 4096 + col] = __float2bfloat16(aco[mi][di][r] / sr[mi][r]);
      }
}

// ---------------------------------------------------------------------------
// Branches 1 (chain) and 2 (pair), flat softmax.
// grid: (B*S = 4096); wave = head-group (4 heads each) for one token.
// ---------------------------------------------------------------------------
__global__ __launch_bounds__(256)
void br12_k(const bf16* __restrict__ qkv, bf16* __restrict__ ctx)
{
  const unsigned short* Q = (const unsigned short*)qkv;
  const int wid = threadIdx.x >> 6, lane = threadIdx.x & 63;
  const int b = blockIdx.x >> 8, i = blockIdx.x & 255;
  const long rowQ = (long)(b*SS + i) * 12288;
  const long rb = (long)(b*SS) * 12288;
  const int jm = i > 0 ? i-1 : 0;
  const int jp = i < SS-1 ? i+1 : SS-1;
  const int j0 = i & ~1, j1 = j0 | 1;
  unsigned short* outp = (unsigned short*)ctx + (long)(b*SS + i) * 4096;
  #pragma unroll
  for (int hh = 0; hh < 4; ++hh) {
    const int h = wid*4 + hh;
    const int off1 = 3072 + h*64 + lane;
    const int off2 = 6144 + h*64 + lane;
    float q1d = bf2f(Q[rowQ + off1]);
    float q2d = bf2f(Q[rowQ + off2]);
    float km = bf2f(Q[rb + (long)jm*12288 + off1 + 1024]);
    float k0 = bf2f(Q[rb + (long)i *12288 + off1 + 1024]);
    float kp = bf2f(Q[rb + (long)jp*12288 + off1 + 1024]);
    float ka = bf2f(Q[rb + (long)j0*12288 + off2 + 1024]);
    float kb_ = bf2f(Q[rb + (long)j1*12288 + off2 + 1024]);
    float s0 = q1d*km, s1 = q1d*k0, s2 = q1d*kp, s3 = q2d*ka, s4 = q2d*kb_;
    #pragma unroll
    for (int st = 1; st < 64; st <<= 1) {
      s0 += __shfl_xor(s0, st); s1 += __shfl_xor(s1, st); s2 += __shfl_xor(s2, st);
      s3 += __shfl_xor(s3, st); s4 += __shfl_xor(s4, st);
    }
    float lm = s0*0.125f + (i > 0      ? 0.f : -1e30f);
    float l0 = s1*0.125f;
    float lp = s2*0.125f + (i < SS-1   ? 0.f : -1e30f);
    float pm = __expf(lm), p0 = __expf(l0), pp = __expf(lp);
    float vm = bf2f(Q[rb + (long)jm*12288 + off1 + 2048]);
    float v0 = bf2f(Q[rb + (long)i *12288 + off1 + 2048]);
    float vp = bf2f(Q[rb + (long)jp*12288 + off1 + 2048]);
    float o1 = (pm*vm + p0*v0 + pp*vp) / (pm+p0+pp);
    float la = s3*0.125f, lb = s4*0.125f;
    float pa = __expf(la), pb = __expf(lb);
    float va = bf2f(Q[rb + (long)j0*12288 + off2 + 2048]);
    float vb2= bf2f(Q[rb + (long)j1*12288 + off2 + 2048]);
    float o2 = (pa*va + pb*vb2) / (pa+pb);
    outp[1024 + h*64 + lane] = (unsigned short)f2bf(o1);
    outp[2048 + h*64 + lane] = (unsigned short)f2bf(o2);
  }
}

// ---------------------------------------------------------------------------
// Fused residual + LayerNorm + adaLN modulation.
// XBF=0: xin fp32; XBF=1: xin bf16. xout (residual stream) stored bf16.
// ---------------------------------------------------------------------------
template<int XBF>
__global__ __launch_bounds__(256)
void ln_fused(const void* __restrict__ xin, const bf16* __restrict__ y,
              int ycnt, long ystride,
              const float* __restrict__ ybias, const float* __restrict__ gate,
              const float* __restrict__ lnw, const float* __restrict__ lnb,
              const float* __restrict__ sc, const float* __restrict__ sh,
              bf16* __restrict__ xout, bf16* __restrict__ xnbf,
              float* __restrict__ xnf)
{
  int row = blockIdx.x;
  int b = row >> 8;
  int t = threadIdx.x;
  int d0 = t * 4;
  float v[4];
  if (XBF) {
    short4v xv = *(const short4v*)((const bf16*)xin + (long)row * DD + d0);
    #pragma unroll
    for (int j = 0; j < 4; ++j) v[j] = bf2f(xv[j]);
  } else {
    f32x4 xi = *(const f32x4*)((const float*)xin + (long)row * DD + d0);
    #pragma unroll
    for (int j = 0; j < 4; ++j) v[j] = xi[j];
  }
  if (y) {
    f32x4 ys = {};
    for (int jp = 0; jp < ycnt; ++jp) {
      short4v yv = *(const short4v*)(y + jp*ystride + (long)row * DD + d0);
      #pragma unroll
      for (int j = 0; j < 4; ++j) ys[j] += bf2f(yv[j]);
    }
    #pragma unroll
    for (int j = 0; j < 4; ++j) {
      float yy = ys[j] + (ybias ? ybias[d0+j] : 0.f);
      v[j] += gate[b*6144 + d0 + j] * yy;
    }
  }
  if (xout) {
    short4v o;
    #pragma unroll
    for (int j = 0; j < 4; ++j) o[j] = f2bf(v[j]);
    *(short4v*)(xout + (long)row * DD + d0) = o;
  }
  float s = v[0]+v[1]+v[2]+v[3];
  float s2 = v[0]*v[0]+v[1]*v[1]+v[2]*v[2]+v[3]*v[3];
  #pragma unroll
  for (int d = 1; d < 64; d <<= 1) { s += __shfl_xor(s, d); s2 += __shfl_xor(s2, d); }
  __shared__ float rs[4][2];
  int wid = t >> 6, lane = t & 63;
  if (lane == 0) { rs[wid][0] = s; rs[wid][1] = s2; }
  __syncthreads();
  s  = rs[0][0]+rs[1][0]+rs[2][0]+rs[3][0];
  s2 = rs[0][1]+rs[1][1]+rs[2][1]+rs[3][1];
  float mean = s * (1.f/1024.f);
  float var  = s2 * (1.f/1024.f) - mean*mean;
  float rstd = rsqrtf(var + 1e-6f);
  #pragma unroll
  for (int j = 0; j < 4; ++j) {
    int d = d0 + j;
    float xn = (v[j] - mean) * rstd * lnw[d] + lnb[d];
    if (sc) {
      float val = xn * (1.f + sc[b*6144 + d]) + sh[b*6144 + d];
      xnbf[(long)row * DD + d] = __float2bfloat16(val);
    } else if (xnbf) {
      xnbf[(long)row * DD + d] = __float2bfloat16(xn);
    } else {
      xnf[(long)row * DD + d] = xn;
    }
  }
}

// ---------------------------------------------------------------------------
// adaLN: fused silu(t_emb) + split-K partial GEMM, then reduce.
// ---------------------------------------------------------------------------
__global__ __launch_bounds__(256)
void a_gemm(const float* __restrict__ Wa, const float* __restrict__ te,
            float* __restrict__ partial)
{
  int l = blockIdx.z, kc = blockIdx.y;
  int n0 = (blockIdx.x * 256 + threadIdx.x) * 4;
  __shared__ float sl[16*128];
  for (int i = threadIdx.x; i < 16*128; i += 256) {
    int m = i >> 7, k = i & 127;
    float v = te[m*1024 + kc*128 + k];
    sl[i] = v / (1.f + __expf(-v));        // fused SiLU
  }
  __syncthreads();
  f32x4 acc[16] = {};
  const float* wp = Wa + (long)l * DD * 6144 + (long)(kc*128) * 6144 + n0;
  #pragma unroll 4
  for (int k = 0; k < 128; ++k) {
    f32x4 w = *(const f32x4*)(wp + (long)k * 6144);
    #pragma unroll
    for (int m = 0; m < 16; ++m) {
      float sv = sl[m*128 + k];
      #pragma unroll
      for (int j = 0; j < 4; ++j) acc[m][j] += sv * w[j];
    }
  }
  #pragma unroll
  for (int m = 0; m < 16; ++m)
    *(f32x4*)(partial + ((long)(l*8 + kc)*16 + m) * 6144 + n0) = acc[m];
}

__global__ __launch_bounds__(256)
void a_red(const float* __restrict__ partial, const float* __restrict__ ba,
           float* __restrict__ a_all)
{
  int idx = blockIdx.x * 256 + threadIdx.x;
  int n = idx % 6144;
  int lm = idx / 6144;
  int l = lm >> 4, m = lm & 15;
  float s = 0.f;
  #pragma unroll
  for (int kc = 0; kc < 8; ++kc)
    s += partial[((long)(l*8 + kc)*16 + m) * 6144 + n];
  a_all[(long)(l*16 + m) * 6144 + n] = s + ba[(long)l * 6144 + n];
}

// ---------------------------------------------------------------------------
// Final projection
// ---------------------------------------------------------------------------
__global__ __launch_bounds__(256)
void proj_k(const float* __restrict__ xnf, const float* __restrict__ Wp,
            const float* __restrict__ bp, float* __restrict__ out)
{
  int v = threadIdx.x & 31, tg = threadIdx.x >> 5;
  int s = blockIdx.x * 8 + tg;
  const float* xr = xnf + (long)s * DD;
  float acc = bp[v];
  #pragma unroll 8
  for (int k = 0; k < DD; ++k) acc += xr[k] * Wp[(long)k * VV + v];
  out[(long)s * VV + v] = acc;
}

// ---------------------------------------------------------------------------
extern "C" void kernel_launch(void* const* d_in, const int* in_sizes, int n_in,
                              void* d_out, int out_size, void* d_ws, size_t ws_size,
                              hipStream_t stream)
{
  (void)in_sizes; (void)n_in; (void)out_size; (void)ws_size;
  const float* x_in = (const float*)d_in[0];
  const float* t_emb= (const float*)d_in[1];
  const float* ln1w = (const float*)d_in[2];
  const float* ln1b = (const float*)d_in[3];
  const float* ln2w = (const float*)d_in[4];
  const float* ln2b = (const float*)d_in[5];
  const float* Wqkv = (const float*)d_in[6];
  const float* Wo   = (const float*)d_in[7];
  const float* Wf   = (const float*)d_in[8];
  const float* bfb  = (const float*)d_in[9];
  const float* W1   = (const float*)d_in[10];
  const float* W3   = (const float*)d_in[11];
  const float* W2   = (const float*)d_in[12];
  const float* Wa   = (const float*)d_in[13];
  const float* ba   = (const float*)d_in[14];
  const float* fnw  = (const float*)d_in[15];
  const float* fnb  = (const float*)d_in[16];
  const float* Wp   = (const float*)d_in[17];
  const float* bp   = (const float*)d_in[18];
  float* out = (float*)d_out;

  char* p = (char*)d_ws;
  auto alloc = [&](size_t bytes) { char* r = p; p += (bytes + 255) & ~(size_t)255; return r; };
  bf16* wqkv_t = (bf16*)alloc(6L*4*3072*1024*2);
  bf16* wo_b   = (bf16*)alloc(6L*4*1024*1024*2);
  bf16* wf_t   = (bf16*)alloc(6L*1024*4096*2);
  bf16* wof_t  = (bf16*)alloc(6L*1024*4096*2);
  bf16* w13i_t = (bf16*)alloc(6L*8192*1024*2);
  bf16* w2_t   = (bf16*)alloc(6L*1024*4096*2);
  float* a_all = (float*)alloc(6L*16*6144*4);
  float* a_par = (float*)alloc(6L*8*16*6144*4);
  bf16* x_buf  = (bf16*)alloc((long)MM*DD*2);      // bf16 residual stream
  bf16* xn     = (bf16*)alloc((long)MM*DD*2);
  char* bufA   = alloc((long)MM*12288*2);          // qkv (branches 1/2 only)
  bf16* vt     = (bf16*)alloc((QKOFF + 2L*2*256*16384)*2);  // vt + packed Q/K
  bf16* ctx    = (bf16*)alloc((long)MM*4096*2);    // K-concat layout
  char* bufB   = alloc((long)MM*4096*2);           // hg | xnf(fp32)
  bf16* gy     = (bf16*)alloc(4L*MM*DD*2);         // 4 bf16 split-K partials

  bf16* qkvb = (bf16*)bufA;
  bf16* hg   = (bf16*)bufB;
  float* xnf = (float*)bufB;
  const long MMDD = (long)MM*DD;

  // --- upfront: adaLN + ALL weight conversions (batched across layers) ---
  a_gemm<<<dim3(6, 8, 6), 256, 0, stream>>>(Wa, t_emb, a_par);
  a_red<<<dim3(2304), 256, 0, stream>>>(a_par, ba, a_all);
  tcvt64<<<dim3(48,16,24),256,0,stream>>>(Wqkv, wqkv_t, 1024, 3072, 1024L*3072, 3072L*1024);
  cvt<<<dim3(12288),256,0,stream>>>(Wo, wo_b);
  tcvt64<<<dim3(16,64,6),256,0,stream>>>(Wf, wf_t, 4096, 1024, 4096L*1024, 4096L*1024);
  tcvt64_w13<<<dim3(64,16,12),256,0,stream>>>(W1, W3, w13i_t);
  tcvt64<<<dim3(16,64,6),256,0,stream>>>(W2, w2_t, 4096, 1024, 4096L*1024, 4096L*1024);
  // Wof[l][x]: z = l*4 + x
  gemm256<bf16,0><<<dim3(4,4,24),512,0,stream>>>(wf_t, wo_b, wof_t,
      1024, 4096, 1024, 4096,
      1024L, 1024L*1024, 1024L, 4,
      1024L*4096, 4L*1024*1024, 1024L*4096, 0, nullptr);

  const long aL = 16L * 6144;
  ln_fused<0><<<4096,256,0,stream>>>(x_in, nullptr, 0, 0, nullptr, nullptr,
                                     ln1w, ln1b, a_all+1024, a_all+0,
                                     nullptr, xn, nullptr);

  for (int l = 0; l < LL; ++l) {
    const float* a_l = a_all + (long)l * aL;
    // QKV with fused V-transpose + Q/K packing for branches 0/3
    gemm256<bf16,2><<<dim3(48,16,1),512,0,stream>>>(xn, wqkv_t + (long)l*4*3072*1024,
        qkvb, 1024, 1024, 1024, 12288, 0,0,0, 1, 0,0,0, 1, vt);
    attn_k<<<dim3(256,2),256,0,stream>>>(vt, ctx);
    br12_k<<<dim3(4096),256,0,stream>>>(qkvb, ctx);
    // gy[z] = ctx @ Wof (split-K=4, bf16 partials)
    gemm256<bf16,0><<<dim3(4,16,4),512,0,stream>>>(ctx, wof_t + (long)l*1024*4096,
        gy, 1024, 4096, 4096, 1024, 1024L, 1024L, MMDD, 4, 0,0,0, 1, nullptr);
    if (l == 0)
      ln_fused<0><<<4096,256,0,stream>>>(x_in, gy, 4, MMDD,
                                         bfb, a_l+2048,
                                         ln2w, ln2b,
                                         a_l+4096, a_l+3072, x_buf, xn, nullptr);
    else
      ln_fused<1><<<4096,256,0,stream>>>(x_buf, gy, 4, MMDD,
                                         bfb + (long)l*1024, a_l+2048,
                                         ln2w + (long)l*1024, ln2b + (long)l*1024,
                                         a_l+4096, a_l+3072, x_buf, xn, nullptr);
    // hg = swiglu(xn @ W13) fused
    gemm256<bf16,1><<<dim3(32,16,1),512,0,stream>>>(xn, w13i_t + (long)l*8192*1024,
        hg, 1024, 1024, 1024, 4096, 0,0,0, 1, 0,0,0, 1, nullptr);
    // gy[z] = hg @ W2 (split-K=4, bf16 partials)
    gemm256<bf16,0><<<dim3(4,16,4),512,0,stream>>>(hg, w2_t + (long)l*1024*4096,
        gy, 1024, 4096, 4096, 1024, 1024L, 1024L, MMDD, 4, 0,0,0, 1, nullptr);
    if (l < LL-1)
      ln_fused<1><<<4096,256,0,stream>>>(x_buf, gy, 4, MMDD, nullptr, a_l+5120,
                                         ln1w + (long)(l+1)*1024, ln1b + (long)(l+1)*1024,
                                         a_all + (long)(l+1)*aL + 1024, a_all + (long)(l+1)*aL,
                                         x_buf, xn, nullptr);
    else
      ln_fused<1><<<4096,256,0,stream>>>(x_buf, gy, 4, MMDD, nullptr, a_l+5120,
                                         fnw, fnb, nullptr, nullptr,
                                         x_buf, nullptr, xnf);
  }
  proj_k<<<dim3(512),256,0,stream>>>(xnf, Wp, bp, out);
}